// Round 1
// baseline (288.571 us; speedup 1.0000x reference)
//
#include <hip/hip_runtime.h>
#include <hip/hip_bf16.h>
#include <cstdint>
#include <cstddef>

typedef __bf16 bf16;
typedef __attribute__((ext_vector_type(8))) __bf16 bf16x8;
typedef __attribute__((ext_vector_type(4))) __bf16 bf16x4;
typedef __attribute__((ext_vector_type(4))) float f32x4;

#define MFMA16x16x32(a, b, c) __builtin_amdgcn_mfma_f32_16x16x32_bf16((a), (b), (c), 0, 0, 0)

__device__ __forceinline__ void gload16(const void* g, void* l) {
  __builtin_amdgcn_global_load_lds((const __attribute__((address_space(1))) unsigned int*)g,
                                   (__attribute__((address_space(3))) unsigned int*)l,
                                   16, 0, 0);
}

// ---------------- fp32 -> bf16 convert (x4 vectorized) ----------------
__global__ __launch_bounds__(256) void cvt_f32_bf16(const float* __restrict__ in,
                                                    bf16* __restrict__ out, int n4) {
  int i = blockIdx.x * 256 + threadIdx.x;
  if (i >= n4) return;
  float4 v = reinterpret_cast<const float4*>(in)[i];
  bf16x4 o;
  o[0] = (bf16)v.x; o[1] = (bf16)v.y; o[2] = (bf16)v.z; o[3] = (bf16)v.w;
  *reinterpret_cast<bf16x4*>(out + (size_t)i * 4) = o;
}

// ---------------- weight convert + transpose: in [R][C] f32 -> out [C][R] bf16 ----------------
__global__ __launch_bounds__(256) void transpose_cvt(const float* __restrict__ in,
                                                     bf16* __restrict__ out, int R, int C) {
  int o = blockIdx.x * 256 + threadIdx.x;
  if (o >= R * C) return;
  int c = o / R;
  int r = o - c * R;
  out[o] = (bf16)in[(size_t)r * C + c];
}

// ---------------- V transpose: V [4096][1024] bf16 -> VT [(b*16+h)*64+d][2048] bf16 ----------------
__global__ __launch_bounds__(256) void transpose_v(const bf16* __restrict__ V,
                                                   bf16* __restrict__ VT) {
  __shared__ __align__(16) bf16 tile[64][72];  // 72 = 64 + 8 pad (keeps 16B row alignment: 144B rows)
  const int tt = blockIdx.x * 64;   // t tile
  const int h = blockIdx.y;         // head
  const int b = blockIdx.z;         // batch
  const int tid = threadIdx.x;
  {
    int r = tid >> 3;             // 0..31
    int c = (tid & 7) * 8;        // 0..56
    const bf16* src = V + ((size_t)(b * 2048 + tt + r)) * 1024 + h * 64 + c;
    *(bf16x8*)&tile[r][c] = *(const bf16x8*)src;
    *(bf16x8*)&tile[r + 32][c] = *(const bf16x8*)(src + (size_t)32 * 1024);
  }
  __syncthreads();
  {
    int d = tid >> 3;             // 0..31
    int tc = (tid & 7) * 8;
    bf16x8 v0, v1;
#pragma unroll
    for (int j = 0; j < 8; ++j) {
      v0[j] = tile[tc + j][d];
      v1[j] = tile[tc + j][d + 32];
    }
    size_t base = ((size_t)((b * 16 + h) * 64 + d)) * 2048 + tt + tc;
    *(bf16x8*)&VT[base] = v0;
    *(bf16x8*)&VT[base + (size_t)32 * 2048] = v1;
  }
}

// ---------------- bf16 MFMA GEMM: C[M,N] = A[M,K] * BT[N,K]^T ----------------
// 4 waves in a WM x WN grid, 16x16x32 MFMA, BK=32, global_load_lds staging.
template <int BM, int BN, int WM, int WN, bool OUT_F32>
__global__ __launch_bounds__(256) void gemm_bf16(const bf16* __restrict__ A,
                                                 const bf16* __restrict__ BT,
                                                 void* __restrict__ C,
                                                 int N, int K) {
  constexpr int BK = 32;
  constexpr int TM = (BM / WM) / 16;
  constexpr int TN = (BN / WN) / 16;
  __shared__ __align__(16) bf16 As[BM * BK];
  __shared__ __align__(16) bf16 Bs[BN * BK];
  const int tid = threadIdx.x;
  const int lane = tid & 63;
  const int wid = tid >> 6;
  const int wm = wid / WN;
  const int wn = wid % WN;
  const int bm = blockIdx.x * BM;
  const int bn = blockIdx.y * BN;
  const int arow = lane & 15;
  const int koff = (lane >> 4) * 8;

  f32x4 acc[TM][TN] = {};

  for (int kb = 0; kb < K; kb += BK) {
    // stage A tile [BM][BK] (rows are 64B)
    for (int base = wid * 1024; base < BM * 64; base += 4096) {
      int off = base + lane * 16;
      int row = off >> 6;
      int col = off & 63;
      gload16((const char*)A + ((size_t)(bm + row) * K + kb) * 2 + col, (char*)As + base);
    }
    // stage BT tile [BN][BK]
    for (int base = wid * 1024; base < BN * 64; base += 4096) {
      int off = base + lane * 16;
      int row = off >> 6;
      int col = off & 63;
      gload16((const char*)BT + ((size_t)(bn + row) * K + kb) * 2 + col, (char*)Bs + base);
    }
    __syncthreads();

    bf16x8 af[TM], bfr[TN];
#pragma unroll
    for (int i = 0; i < TM; ++i)
      af[i] = *(const bf16x8*)&As[(wm * TM * 16 + i * 16 + arow) * BK + koff];
#pragma unroll
    for (int j = 0; j < TN; ++j)
      bfr[j] = *(const bf16x8*)&Bs[(wn * TN * 16 + j * 16 + arow) * BK + koff];
#pragma unroll
    for (int i = 0; i < TM; ++i)
#pragma unroll
      for (int j = 0; j < TN; ++j)
        acc[i][j] = MFMA16x16x32(af[i], bfr[j], acc[i][j]);
    __syncthreads();
  }

  const int m0 = bm + wm * TM * 16 + (lane >> 4) * 4;
  const int n0 = bn + wn * TN * 16 + (lane & 15);
#pragma unroll
  for (int i = 0; i < TM; ++i)
#pragma unroll
    for (int j = 0; j < TN; ++j)
#pragma unroll
      for (int r = 0; r < 4; ++r) {
        int m = m0 + i * 16 + r;
        int n = n0 + j * 16;
        float v = acc[i][j][r];
        if constexpr (OUT_F32)
          ((float*)C)[(size_t)m * N + n] = v;
        else
          ((bf16*)C)[(size_t)m * N + n] = (bf16)v;
      }
}

// ---------------- flash attention (causal, per-head) ----------------
// Q,K: [4096][1024] bf16 (row = b*2048+t, col = h*64+d); VT: [(b*16+h)*64+d][2048]
// O: [4096][1024] bf16. Block: 64 q-rows (16 per wave), KB=32 kv tiles.
__global__ __launch_bounds__(256) void mla_attn(const bf16* __restrict__ Q,
                                                const bf16* __restrict__ Kb,
                                                const bf16* __restrict__ VT,
                                                bf16* __restrict__ O) {
  constexpr int KB = 32;
  const int qtile = blockIdx.x;
  const int bh = blockIdx.y;
  const int b = bh >> 4, h = bh & 15;
  const int tid = threadIdx.x, lane = tid & 63, w = tid >> 6;
  const int qbase = qtile * 64;
  const int arow = lane & 15;
  const int grp = lane >> 4;

  __shared__ __align__(16) bf16 Ks[KB * 64];       // [32 keys][64 d]
  __shared__ __align__(16) bf16 Vs[64 * KB];       // [64 d][32 keys]
  __shared__ __align__(16) bf16 Ps[4][16 * KB];    // per-wave P tile [16 q][32 keys]

  // Q fragments: wave w owns q-rows qbase+w*16 .. +15
  bf16x8 qf[2];
  {
    const int qrow = qbase + w * 16 + arow;
    const bf16* qptr = Q + ((size_t)(b * 2048 + qrow)) * 1024 + h * 64 + grp * 8;
    qf[0] = *(const bf16x8*)qptr;
    qf[1] = *(const bf16x8*)(qptr + 32);
  }

  float m_r[4] = {-1e30f, -1e30f, -1e30f, -1e30f};
  float l_r[4] = {0.f, 0.f, 0.f, 0.f};
  f32x4 oacc[4] = {};

  const int ntiles = (qbase + 63) / KB + 1;
  for (int t = 0; t < ntiles; ++t) {
    const int kbase = t * KB;
    // stage K tile (4KB, one issue per wave) and VT tile (4KB)
    {
      int base = w * 1024;
      int off = base + lane * 16;
      int row = off >> 7, col = off & 127;
      gload16((const char*)(Kb + ((size_t)(b * 2048 + kbase + row)) * 1024 + h * 64) + col,
              (char*)Ks + base);
    }
    {
      int base = w * 1024;
      int off = base + lane * 16;
      int row = off >> 6, col = off & 63;
      gload16((const char*)(VT + ((size_t)(bh * 64 + row)) * 2048 + kbase) + col,
              (char*)Vs + base);
    }
    __syncthreads();

    // S = Q K^T for this wave's 16 rows x 32 keys
    f32x4 s[2] = {};
#pragma unroll
    for (int kb2 = 0; kb2 < 2; ++kb2) {
#pragma unroll
      for (int dc = 0; dc < 2; ++dc) {
        bf16x8 kf = *(const bf16x8*)&Ks[(kb2 * 16 + arow) * 64 + dc * 32 + grp * 8];
        s[kb2] = MFMA16x16x32(qf[dc], kf, s[kb2]);
      }
    }

    const int qrow0 = qbase + w * 16 + grp * 4;
    const bool need_mask = (kbase + KB - 1) > (qbase + w * 16);
    float sv[2][4];
#pragma unroll
    for (int kb2 = 0; kb2 < 2; ++kb2)
#pragma unroll
      for (int r = 0; r < 4; ++r) {
        float v = s[kb2][r] * 0.125f;
        if (need_mask) {
          int kg = kbase + kb2 * 16 + arow;
          if (kg > qrow0 + r) v = -1e30f;
        }
        sv[kb2][r] = v;
      }

    // online softmax (rows live in 16-lane groups; xor<16 stays in group)
    float alpha[4];
#pragma unroll
    for (int r = 0; r < 4; ++r) {
      float mx = fmaxf(sv[0][r], sv[1][r]);
      mx = fmaxf(mx, __shfl_xor(mx, 1));
      mx = fmaxf(mx, __shfl_xor(mx, 2));
      mx = fmaxf(mx, __shfl_xor(mx, 4));
      mx = fmaxf(mx, __shfl_xor(mx, 8));
      float mnew = fmaxf(m_r[r], mx);
      alpha[r] = __expf(m_r[r] - mnew);
      m_r[r] = mnew;
      float rs = 0.f;
#pragma unroll
      for (int kb2 = 0; kb2 < 2; ++kb2) {
        float p = __expf(sv[kb2][r] - mnew);
        sv[kb2][r] = p;
        rs += p;
      }
      rs += __shfl_xor(rs, 1);
      rs += __shfl_xor(rs, 2);
      rs += __shfl_xor(rs, 4);
      rs += __shfl_xor(rs, 8);
      l_r[r] = l_r[r] * alpha[r] + rs;
    }

    // rescale O accumulator
#pragma unroll
    for (int db = 0; db < 4; ++db)
#pragma unroll
      for (int r = 0; r < 4; ++r)
        oacc[db][r] *= alpha[r];

    // P (D-layout) -> LDS -> A-frag layout
#pragma unroll
    for (int kb2 = 0; kb2 < 2; ++kb2)
#pragma unroll
      for (int r = 0; r < 4; ++r)
        Ps[w][(grp * 4 + r) * KB + kb2 * 16 + arow] = (bf16)sv[kb2][r];
    __syncthreads();

    bf16x8 pf = *(const bf16x8*)&Ps[w][arow * KB + grp * 8];
#pragma unroll
    for (int db = 0; db < 4; ++db) {
      bf16x8 vf = *(const bf16x8*)&Vs[(db * 16 + arow) * KB + grp * 8];
      oacc[db] = MFMA16x16x32(pf, vf, oacc[db]);
    }
    __syncthreads();
  }

  // epilogue
  const int qg = qbase + w * 16 + grp * 4;
#pragma unroll
  for (int db = 0; db < 4; ++db) {
#pragma unroll
    for (int r = 0; r < 4; ++r) {
      float v = oacc[db][r] / l_r[r];
      O[((size_t)(b * 2048 + qg + r)) * 1024 + h * 64 + db * 16 + arow] = (bf16)v;
    }
  }
}

// ---------------- host launch ----------------
extern "C" void kernel_launch(void* const* d_in, const int* in_sizes, int n_in,
                              void* d_out, int out_size, void* d_ws, size_t ws_size,
                              hipStream_t stream) {
  const float* x   = (const float*)d_in[0];  // [2,2048,1024]
  const float* w_c = (const float*)d_in[1];  // [1024,64]
  const float* w_k = (const float*)d_in[2];  // [64,1024]
  const float* w_v = (const float*)d_in[3];  // [64,1024]
  const float* w_q = (const float*)d_in[4];  // [1024,1024]
  const float* w_o = (const float*)d_in[5];  // [1024,1024]
  float* out = (float*)d_out;

  char* ws = (char*)d_ws;
  size_t off = 0;
  auto alloc = [&](size_t bytes) {
    char* p = ws + off;
    off += (bytes + 255) & ~(size_t)255;
    return p;
  };
  bf16* xb      = (bf16*)alloc((size_t)4096 * 1024 * 2);
  bf16* latentb = (bf16*)alloc((size_t)4096 * 64 * 2);
  bf16* Kbuf    = (bf16*)alloc((size_t)4096 * 1024 * 2);
  bf16* Vbuf    = (bf16*)alloc((size_t)4096 * 1024 * 2);
  bf16* VTbuf   = (bf16*)alloc((size_t)2048 * 2048 * 2);
  bf16* Qbuf    = (bf16*)alloc((size_t)4096 * 1024 * 2);
  bf16* Obuf    = (bf16*)alloc((size_t)4096 * 1024 * 2);
  bf16* wcT     = (bf16*)alloc((size_t)64 * 1024 * 2);
  bf16* wkT     = (bf16*)alloc((size_t)1024 * 64 * 2);
  bf16* wvT     = (bf16*)alloc((size_t)1024 * 64 * 2);
  bf16* wqT     = (bf16*)alloc((size_t)1024 * 1024 * 2);
  bf16* woT     = (bf16*)alloc((size_t)1024 * 1024 * 2);

  // conversions
  cvt_f32_bf16<<<4096, 256, 0, stream>>>(x, xb, 1048576);          // 4096*1024/4
  transpose_cvt<<<256, 256, 0, stream>>>(w_c, wcT, 1024, 64);
  transpose_cvt<<<256, 256, 0, stream>>>(w_k, wkT, 64, 1024);
  transpose_cvt<<<256, 256, 0, stream>>>(w_v, wvT, 64, 1024);
  transpose_cvt<<<4096, 256, 0, stream>>>(w_q, wqT, 1024, 1024);
  transpose_cvt<<<4096, 256, 0, stream>>>(w_o, woT, 1024, 1024);

  // latent = x @ w_c : [4096,64]
  gemm_bf16<128, 64, 2, 2, false><<<dim3(32, 1), 256, 0, stream>>>(xb, wcT, latentb, 64, 1024);
  // K = latent @ w_k : [4096,1024]
  gemm_bf16<128, 128, 2, 2, false><<<dim3(32, 8), 256, 0, stream>>>(latentb, wkT, Kbuf, 1024, 64);
  // V = latent @ w_v
  gemm_bf16<128, 128, 2, 2, false><<<dim3(32, 8), 256, 0, stream>>>(latentb, wvT, Vbuf, 1024, 64);
  // VT
  transpose_v<<<dim3(32, 16, 2), 256, 0, stream>>>(Vbuf, VTbuf);
  // Q = x @ w_q
  gemm_bf16<128, 128, 2, 2, false><<<dim3(32, 8), 256, 0, stream>>>(xb, wqT, Qbuf, 1024, 1024);
  // attention
  mla_attn<<<dim3(32, 32), 256, 0, stream>>>(Qbuf, Kbuf, VTbuf, Obuf);
  // out = O @ w_o (fp32 out)
  gemm_bf16<128, 128, 2, 2, true><<<dim3(32, 8), 256, 0, stream>>>(Obuf, woT, (void*)out, 1024, 1024);

  (void)in_sizes; (void)n_in; (void)out_size; (void)ws_size;
}

// Round 2
// 243.506 us; speedup vs baseline: 1.1851x; 1.1851x over previous
//
#include <hip/hip_runtime.h>
#include <hip/hip_bf16.h>
#include <cstdint>
#include <cstddef>

typedef __bf16 bf16;
typedef __attribute__((ext_vector_type(8))) __bf16 bf16x8;
typedef __attribute__((ext_vector_type(4))) __bf16 bf16x4;
typedef __attribute__((ext_vector_type(4))) float f32x4;

#define MFMA16x16x32(a, b, c) __builtin_amdgcn_mfma_f32_16x16x32_bf16((a), (b), (c), 0, 0, 0)

__device__ __forceinline__ void gload16(const void* g, void* l) {
  __builtin_amdgcn_global_load_lds((const __attribute__((address_space(1))) unsigned int*)g,
                                   (__attribute__((address_space(3))) unsigned int*)l,
                                   16, 0, 0);
}

// ---------------- fp32 -> bf16 convert (x4 vectorized) ----------------
__global__ __launch_bounds__(256) void cvt_f32_bf16(const float* __restrict__ in,
                                                    bf16* __restrict__ out, int n4) {
  int i = blockIdx.x * 256 + threadIdx.x;
  if (i >= n4) return;
  float4 v = reinterpret_cast<const float4*>(in)[i];
  bf16x4 o;
  o[0] = (bf16)v.x; o[1] = (bf16)v.y; o[2] = (bf16)v.z; o[3] = (bf16)v.w;
  *reinterpret_cast<bf16x4*>(out + (size_t)i * 4) = o;
}

// ---------------- weight convert + transpose: in [R][C] f32 -> out [C][R] bf16 ----------------
__global__ __launch_bounds__(256) void transpose_cvt(const float* __restrict__ in,
                                                     bf16* __restrict__ out, int R, int C) {
  int o = blockIdx.x * 256 + threadIdx.x;
  if (o >= R * C) return;
  int c = o / R;
  int r = o - c * R;
  out[o] = (bf16)in[(size_t)r * C + c];
}

// ---------------- V transpose: V [4096][1024] bf16 -> VT [(b*16+h)*64+d][2048] bf16 ----------------
__global__ __launch_bounds__(256) void transpose_v(const bf16* __restrict__ V,
                                                   bf16* __restrict__ VT) {
  __shared__ __align__(16) bf16 tile[64][72];
  const int tt = blockIdx.x * 64;
  const int h = blockIdx.y;
  const int b = blockIdx.z;
  const int tid = threadIdx.x;
  {
    int r = tid >> 3;
    int c = (tid & 7) * 8;
    const bf16* src = V + ((size_t)(b * 2048 + tt + r)) * 1024 + h * 64 + c;
    *(bf16x8*)&tile[r][c] = *(const bf16x8*)src;
    *(bf16x8*)&tile[r + 32][c] = *(const bf16x8*)(src + (size_t)32 * 1024);
  }
  __syncthreads();
  {
    int d = tid >> 3;
    int tc = (tid & 7) * 8;
    bf16x8 v0, v1;
#pragma unroll
    for (int j = 0; j < 8; ++j) {
      v0[j] = tile[tc + j][d];
      v1[j] = tile[tc + j][d + 32];
    }
    size_t base = ((size_t)((b * 16 + h) * 64 + d)) * 2048 + tt + tc;
    *(bf16x8*)&VT[base] = v0;
    *(bf16x8*)&VT[base + (size_t)32 * 2048] = v1;
  }
}

// ---------------- bf16 MFMA GEMM: C[M,N] = A[M,K] * BT[N,K]^T ----------------
template <int BM, int BN, int WM, int WN, bool OUT_F32>
__global__ __launch_bounds__(256) void gemm_bf16(const bf16* __restrict__ A,
                                                 const bf16* __restrict__ BT,
                                                 void* __restrict__ C,
                                                 int N, int K) {
  constexpr int BK = 32;
  constexpr int TM = (BM / WM) / 16;
  constexpr int TN = (BN / WN) / 16;
  __shared__ __align__(16) bf16 As[BM * BK];
  __shared__ __align__(16) bf16 Bs[BN * BK];
  const int tid = threadIdx.x;
  const int lane = tid & 63;
  const int wid = tid >> 6;
  const int wm = wid / WN;
  const int wn = wid % WN;
  const int bm = blockIdx.x * BM;
  const int bn = blockIdx.y * BN;
  const int arow = lane & 15;
  const int koff = (lane >> 4) * 8;

  f32x4 acc[TM][TN] = {};

  for (int kb = 0; kb < K; kb += BK) {
    for (int base = wid * 1024; base < BM * 64; base += 4096) {
      int off = base + lane * 16;
      int row = off >> 6;
      int col = off & 63;
      gload16((const char*)A + ((size_t)(bm + row) * K + kb) * 2 + col, (char*)As + base);
    }
    for (int base = wid * 1024; base < BN * 64; base += 4096) {
      int off = base + lane * 16;
      int row = off >> 6;
      int col = off & 63;
      gload16((const char*)BT + ((size_t)(bn + row) * K + kb) * 2 + col, (char*)Bs + base);
    }
    __syncthreads();

    bf16x8 af[TM], bfr[TN];
#pragma unroll
    for (int i = 0; i < TM; ++i)
      af[i] = *(const bf16x8*)&As[(wm * TM * 16 + i * 16 + arow) * BK + koff];
#pragma unroll
    for (int j = 0; j < TN; ++j)
      bfr[j] = *(const bf16x8*)&Bs[(wn * TN * 16 + j * 16 + arow) * BK + koff];
#pragma unroll
    for (int i = 0; i < TM; ++i)
#pragma unroll
      for (int j = 0; j < TN; ++j)
        acc[i][j] = MFMA16x16x32(af[i], bfr[j], acc[i][j]);
    __syncthreads();
  }

  const int m0 = bm + wm * TM * 16 + (lane >> 4) * 4;
  const int n0 = bn + wn * TN * 16 + (lane & 15);
#pragma unroll
  for (int i = 0; i < TM; ++i)
#pragma unroll
    for (int j = 0; j < TN; ++j)
#pragma unroll
      for (int r = 0; r < 4; ++r) {
        int m = m0 + i * 16 + r;
        int n = n0 + j * 16;
        float v = acc[i][j][r];
        if constexpr (OUT_F32)
          ((float*)C)[(size_t)m * N + n] = v;
        else
          ((bf16*)C)[(size_t)m * N + n] = (bf16)v;
      }
}

// ---------------- flash attention v2 (causal, per-head) ----------------
// 128 q-rows/block (32 per wave, TM=2), KB=64 kv tiles, double-buffered LDS with
// counted vmcnt, XOR-swizzled LDS (byte ^= (row&7)<<4) on Ks/Vs/Ps.
// Q,K: [4096][1024] bf16; VT: [(b*16+h)*64+d][2048]; O: [4096][1024] bf16.
__global__ __launch_bounds__(256) void mla_attn(const bf16* __restrict__ Q,
                                                const bf16* __restrict__ Kb,
                                                const bf16* __restrict__ VT,
                                                bf16* __restrict__ O) {
  constexpr int KB = 64;
  const int qt = (int)(gridDim.x - 1 - blockIdx.x);  // longest blocks first
  const int bh = blockIdx.y;
  const int b = bh >> 4, h = bh & 15;
  const int tid = threadIdx.x, lane = tid & 63, w = tid >> 6;
  const int qbase = qt * 128;
  const int arow = lane & 15;
  const int grp = lane >> 4;

  __shared__ __align__(16) bf16 Ks[2][64 * 64];   // [buf][key row][d], swizzled, 8 KB each
  __shared__ __align__(16) bf16 Vs[2][64 * 64];   // [buf][d row][key], swizzled
  __shared__ __align__(16) bf16 Ps[4][32 * 64];   // per-wave [q row][key], swizzled

  // Q fragments: wave w owns q rows qbase + w*32 .. +31 (two 16-row sub-tiles)
  bf16x8 qf[2][2];
#pragma unroll
  for (int tm = 0; tm < 2; ++tm) {
    const int qrow = qbase + w * 32 + tm * 16 + arow;
    const bf16* qptr = Q + ((size_t)(b * 2048 + qrow)) * 1024 + h * 64 + grp * 8;
    qf[tm][0] = *(const bf16x8*)qptr;
    qf[tm][1] = *(const bf16x8*)(qptr + 32);
  }
  asm volatile("s_waitcnt vmcnt(0)" ::: "memory");  // drain Q loads so loop vmcnt counts only staging

  // stage one 64-key tile: K 8KB + V 8KB, 4 gload16 issues per wave (1KB each)
  auto stage = [&](int buf, int kbase) {
#pragma unroll
    for (int i = 0; i < 2; ++i) {
      const int base = w * 2048 + i * 1024;
      const int dst = base + lane * 16;
      const int row = dst >> 7;
      const int cp = dst & 127;
      const int src_c = cp ^ ((row & 7) << 4);  // inverse-swizzled global source
      gload16((const char*)Kb + ((size_t)(b * 2048 + kbase + row) * 1024 + h * 64) * 2 + src_c,
              (char*)&Ks[buf][0] + base);
    }
#pragma unroll
    for (int i = 0; i < 2; ++i) {
      const int base = w * 2048 + i * 1024;
      const int dst = base + lane * 16;
      const int drow = dst >> 7;
      const int cp = dst & 127;
      const int src_c = cp ^ ((drow & 7) << 4);
      gload16((const char*)VT + ((size_t)(bh * 64 + drow) * 2048 + kbase) * 2 + src_c,
              (char*)&Vs[buf][0] + base);
    }
  };

  float m_r[2][4], l_r[2][4];
  f32x4 oacc[2][4] = {};
#pragma unroll
  for (int tm = 0; tm < 2; ++tm)
#pragma unroll
    for (int r = 0; r < 4; ++r) { m_r[tm][r] = -1e30f; l_r[tm][r] = 0.f; }

  stage(0, 0);
  const int ntiles = 2 * qt + 2;
  for (int t = 0; t < ntiles; ++t) {
    const int cur = t & 1;
    const int kbase = t * KB;
    if (t + 1 < ntiles) {
      stage(cur ^ 1, kbase + KB);
      asm volatile("s_waitcnt vmcnt(4)" ::: "memory");  // wait for buf[cur] only; prefetch stays in flight
    } else {
      asm volatile("s_waitcnt vmcnt(0)" ::: "memory");
    }
    __builtin_amdgcn_s_barrier();
    __builtin_amdgcn_sched_barrier(0);

    // K fragments (swizzled read)
    bf16x8 kf[4][2];
#pragma unroll
    for (int kb2 = 0; kb2 < 4; ++kb2)
#pragma unroll
      for (int dc = 0; dc < 2; ++dc) {
        const int krow = kb2 * 16 + arow;
        const int kbyte = krow * 128 + ((dc * 64 + grp * 16) ^ ((krow & 7) << 4));
        kf[kb2][dc] = *(const bf16x8*)((const char*)&Ks[cur][0] + kbyte);
      }

#pragma unroll
    for (int tm = 0; tm < 2; ++tm) {
      f32x4 s[4] = {};
#pragma unroll
      for (int kb2 = 0; kb2 < 4; ++kb2)
#pragma unroll
        for (int dc = 0; dc < 2; ++dc)
          s[kb2] = MFMA16x16x32(qf[tm][dc], kf[kb2][dc], s[kb2]);

      const int q0 = qbase + w * 32 + tm * 16;
      const int qrow0 = q0 + grp * 4;
      const bool need_mask = (kbase + KB - 1) > q0;
      float p[4][4];
#pragma unroll
      for (int kb2 = 0; kb2 < 4; ++kb2)
#pragma unroll
        for (int r = 0; r < 4; ++r) {
          float v = s[kb2][r] * 0.18033688011112042f;  // 0.125 * log2(e); exp via exp2
          if (need_mask && (kbase + kb2 * 16 + arow > qrow0 + r)) v = -1e30f;
          p[kb2][r] = v;
        }
#pragma unroll
      for (int r = 0; r < 4; ++r) {
        float mx = fmaxf(fmaxf(p[0][r], p[1][r]), fmaxf(p[2][r], p[3][r]));
        mx = fmaxf(mx, __shfl_xor(mx, 1));
        mx = fmaxf(mx, __shfl_xor(mx, 2));
        mx = fmaxf(mx, __shfl_xor(mx, 4));
        mx = fmaxf(mx, __shfl_xor(mx, 8));
        const float mnew = fmaxf(m_r[tm][r], mx);
        const float alpha = exp2f(m_r[tm][r] - mnew);
        m_r[tm][r] = mnew;
        float rs = 0.f;
#pragma unroll
        for (int kb2 = 0; kb2 < 4; ++kb2) {
          const float e = exp2f(p[kb2][r] - mnew);
          p[kb2][r] = e;
          rs += e;
        }
        rs += __shfl_xor(rs, 1);
        rs += __shfl_xor(rs, 2);
        rs += __shfl_xor(rs, 4);
        rs += __shfl_xor(rs, 8);
        l_r[tm][r] = l_r[tm][r] * alpha + rs;
#pragma unroll
        for (int db = 0; db < 4; ++db)
          oacc[tm][db][r] *= alpha;
      }
      // P (D-layout) -> per-wave swizzled LDS tile
#pragma unroll
      for (int kb2 = 0; kb2 < 4; ++kb2)
#pragma unroll
        for (int r = 0; r < 4; ++r) {
          const int prow = tm * 16 + grp * 4 + r;
          const int pbyte = prow * 128 + (((kb2 * 16 + arow) * 2) ^ ((prow & 7) << 4));
          *(bf16*)((char*)&Ps[w][0] + pbyte) = (bf16)p[kb2][r];
        }
    }

    // PV: O += P[32 q][64 k] * V^T[64 k][64 d]
    bf16x8 vf[4][2], pf[2][2];
#pragma unroll
    for (int db = 0; db < 4; ++db)
#pragma unroll
      for (int kb = 0; kb < 2; ++kb) {
        const int drow = db * 16 + arow;
        const int vbyte = drow * 128 + ((kb * 64 + grp * 16) ^ ((drow & 7) << 4));
        vf[db][kb] = *(const bf16x8*)((const char*)&Vs[cur][0] + vbyte);
      }
#pragma unroll
    for (int tm = 0; tm < 2; ++tm)
#pragma unroll
      for (int kb = 0; kb < 2; ++kb) {
        const int prow = tm * 16 + arow;
        const int pbyte = prow * 128 + ((kb * 64 + grp * 16) ^ ((prow & 7) << 4));
        pf[tm][kb] = *(const bf16x8*)((const char*)&Ps[w][0] + pbyte);
      }
#pragma unroll
    for (int tm = 0; tm < 2; ++tm)
#pragma unroll
      for (int db = 0; db < 4; ++db)
#pragma unroll
        for (int kb = 0; kb < 2; ++kb)
          oacc[tm][db] = MFMA16x16x32(pf[tm][kb], vf[db][kb], oacc[tm][db]);

    __builtin_amdgcn_sched_barrier(0);
    asm volatile("s_waitcnt lgkmcnt(0)" ::: "memory");
    __builtin_amdgcn_s_barrier();  // all waves done reading buf[cur]; next iter may overwrite it
  }

  // epilogue
#pragma unroll
  for (int tm = 0; tm < 2; ++tm)
#pragma unroll
    for (int r = 0; r < 4; ++r) {
      const float inv = 1.0f / l_r[tm][r];
      const int qrow = qbase + w * 32 + tm * 16 + grp * 4 + r;
#pragma unroll
      for (int db = 0; db < 4; ++db)
        O[((size_t)(b * 2048 + qrow)) * 1024 + h * 64 + db * 16 + arow] =
            (bf16)(oacc[tm][db][r] * inv);
    }
}

// ---------------- host launch ----------------
extern "C" void kernel_launch(void* const* d_in, const int* in_sizes, int n_in,
                              void* d_out, int out_size, void* d_ws, size_t ws_size,
                              hipStream_t stream) {
  const float* x   = (const float*)d_in[0];
  const float* w_c = (const float*)d_in[1];
  const float* w_k = (const float*)d_in[2];
  const float* w_v = (const float*)d_in[3];
  const float* w_q = (const float*)d_in[4];
  const float* w_o = (const float*)d_in[5];
  float* out = (float*)d_out;

  char* ws = (char*)d_ws;
  size_t off = 0;
  auto alloc = [&](size_t bytes) {
    char* p = ws + off;
    off += (bytes + 255) & ~(size_t)255;
    return p;
  };
  bf16* xb      = (bf16*)alloc((size_t)4096 * 1024 * 2);
  bf16* latentb = (bf16*)alloc((size_t)4096 * 64 * 2);
  bf16* Kbuf    = (bf16*)alloc((size_t)4096 * 1024 * 2);
  bf16* Vbuf    = (bf16*)alloc((size_t)4096 * 1024 * 2);
  bf16* VTbuf   = (bf16*)alloc((size_t)2048 * 2048 * 2);
  bf16* Qbuf    = (bf16*)alloc((size_t)4096 * 1024 * 2);
  bf16* Obuf    = (bf16*)alloc((size_t)4096 * 1024 * 2);
  bf16* wcT     = (bf16*)alloc((size_t)64 * 1024 * 2);
  bf16* wkT     = (bf16*)alloc((size_t)1024 * 64 * 2);
  bf16* wvT     = (bf16*)alloc((size_t)1024 * 64 * 2);
  bf16* wqT     = (bf16*)alloc((size_t)1024 * 1024 * 2);
  bf16* woT     = (bf16*)alloc((size_t)1024 * 1024 * 2);

  cvt_f32_bf16<<<4096, 256, 0, stream>>>(x, xb, 1048576);
  transpose_cvt<<<256, 256, 0, stream>>>(w_c, wcT, 1024, 64);
  transpose_cvt<<<256, 256, 0, stream>>>(w_k, wkT, 64, 1024);
  transpose_cvt<<<256, 256, 0, stream>>>(w_v, wvT, 64, 1024);
  transpose_cvt<<<4096, 256, 0, stream>>>(w_q, wqT, 1024, 1024);
  transpose_cvt<<<4096, 256, 0, stream>>>(w_o, woT, 1024, 1024);

  gemm_bf16<128, 64, 2, 2, false><<<dim3(32, 1), 256, 0, stream>>>(xb, wcT, latentb, 64, 1024);
  gemm_bf16<128, 128, 2, 2, false><<<dim3(32, 8), 256, 0, stream>>>(latentb, wkT, Kbuf, 1024, 64);
  gemm_bf16<128, 128, 2, 2, false><<<dim3(32, 8), 256, 0, stream>>>(latentb, wvT, Vbuf, 1024, 64);
  transpose_v<<<dim3(32, 16, 2), 256, 0, stream>>>(Vbuf, VTbuf);
  gemm_bf16<128, 128, 2, 2, false><<<dim3(32, 8), 256, 0, stream>>>(xb, wqT, Qbuf, 1024, 1024);
  mla_attn<<<dim3(16, 32), 256, 0, stream>>>(Qbuf, Kbuf, VTbuf, Obuf);
  gemm_bf16<128, 128, 2, 2, true><<<dim3(32, 8), 256, 0, stream>>>(Obuf, woT, (void*)out, 1024, 1024);

  (void)in_sizes; (void)n_in; (void)out_size; (void)ws_size;
}

// Round 3
// 186.319 us; speedup vs baseline: 1.5488x; 1.3069x over previous
//
#include <hip/hip_runtime.h>
#include <hip/hip_bf16.h>
#include <cstdint>
#include <cstddef>

typedef __bf16 bf16;
typedef __attribute__((ext_vector_type(8))) __bf16 bf16x8;
typedef __attribute__((ext_vector_type(4))) __bf16 bf16x4;
typedef __attribute__((ext_vector_type(4))) float f32x4;

#define MFMA16x16x32(a, b, c) __builtin_amdgcn_mfma_f32_16x16x32_bf16((a), (b), (c), 0, 0, 0)

__device__ __forceinline__ void gload16(const void* g, void* l) {
  __builtin_amdgcn_global_load_lds((const __attribute__((address_space(1))) unsigned int*)g,
                                   (__attribute__((address_space(3))) unsigned int*)l,
                                   16, 0, 0);
}

// ---------------- fp32 -> bf16 convert (x4 vectorized) ----------------
__global__ __launch_bounds__(256) void cvt_f32_bf16(const float* __restrict__ in,
                                                    bf16* __restrict__ out, int n4) {
  int i = blockIdx.x * 256 + threadIdx.x;
  if (i >= n4) return;
  float4 v = reinterpret_cast<const float4*>(in)[i];
  bf16x4 o;
  o[0] = (bf16)v.x; o[1] = (bf16)v.y; o[2] = (bf16)v.z; o[3] = (bf16)v.w;
  *reinterpret_cast<bf16x4*>(out + (size_t)i * 4) = o;
}

// ------------- tiled transpose+convert: in [R][C] f32 -> out [C][R] bf16 -------------
// R, C multiples of 64. Coalesced float4 reads, coalesced bf16x8 writes.
__global__ __launch_bounds__(256) void transpose_cvt_tiled(const float* __restrict__ in,
                                                           bf16* __restrict__ out,
                                                           int R, int C) {
  __shared__ __align__(16) bf16 tile[64][72];
  const int c0 = blockIdx.x * 64, r0 = blockIdx.y * 64;
  const int tid = threadIdx.x;
  {
    int rr = tid >> 4;
    int cc = (tid & 15) * 4;
#pragma unroll
    for (int p = 0; p < 4; ++p) {
      float4 v = *(const float4*)&in[(size_t)(r0 + rr + 16 * p) * C + c0 + cc];
      bf16x4 o;
      o[0] = (bf16)v.x; o[1] = (bf16)v.y; o[2] = (bf16)v.z; o[3] = (bf16)v.w;
      *(bf16x4*)&tile[rr + 16 * p][cc] = o;
    }
  }
  __syncthreads();
  {
    int cc = tid >> 3;
    int rr = (tid & 7) * 8;
#pragma unroll
    for (int p = 0; p < 2; ++p) {
      bf16x8 v;
#pragma unroll
      for (int j = 0; j < 8; ++j) v[j] = tile[rr + j][cc + 32 * p];
      *(bf16x8*)&out[(size_t)(c0 + cc + 32 * p) * R + r0 + rr] = v;
    }
  }
}

// ------------- V transpose: KV [4096][2048] bf16 (V in cols 1024+) -> VT [(bh)*64+d][2048] -------------
__global__ __launch_bounds__(256) void transpose_v(const bf16* __restrict__ KV,
                                                   bf16* __restrict__ VT) {
  __shared__ __align__(16) bf16 tile[64][72];
  const int tt = blockIdx.x * 64;
  const int h = blockIdx.y;
  const int b = blockIdx.z;
  const int tid = threadIdx.x;
  {
    int r = tid >> 3;
    int c = (tid & 7) * 8;
    const bf16* src = KV + ((size_t)(b * 2048 + tt + r)) * 2048 + 1024 + h * 64 + c;
    *(bf16x8*)&tile[r][c] = *(const bf16x8*)src;
    *(bf16x8*)&tile[r + 32][c] = *(const bf16x8*)(src + (size_t)32 * 2048);
  }
  __syncthreads();
  {
    int d = tid >> 3;
    int tc = (tid & 7) * 8;
    bf16x8 v0, v1;
#pragma unroll
    for (int j = 0; j < 8; ++j) {
      v0[j] = tile[tc + j][d];
      v1[j] = tile[tc + j][d + 32];
    }
    size_t base = ((size_t)((b * 16 + h) * 64 + d)) * 2048 + tt + tc;
    *(bf16x8*)&VT[base] = v0;
    *(bf16x8*)&VT[base + (size_t)32 * 2048] = v1;
  }
}

// ---------------- bf16 MFMA GEMM: C[M,N] = A[M,K] * BT[N,K]^T ----------------
template <int BM, int BN, int WM, int WN, bool OUT_F32>
__global__ __launch_bounds__(256) void gemm_bf16(const bf16* __restrict__ A,
                                                 const bf16* __restrict__ BT,
                                                 void* __restrict__ C,
                                                 int N, int K) {
  constexpr int BK = 32;
  constexpr int TM = (BM / WM) / 16;
  constexpr int TN = (BN / WN) / 16;
  __shared__ __align__(16) bf16 As[BM * BK];
  __shared__ __align__(16) bf16 Bs[BN * BK];
  const int tid = threadIdx.x;
  const int lane = tid & 63;
  const int wid = tid >> 6;
  const int wm = wid / WN;
  const int wn = wid % WN;
  const int bm = blockIdx.x * BM;
  const int bn = blockIdx.y * BN;
  const int arow = lane & 15;
  const int koff = (lane >> 4) * 8;

  f32x4 acc[TM][TN] = {};

  for (int kb = 0; kb < K; kb += BK) {
    for (int base = wid * 1024; base < BM * 64; base += 4096) {
      int off = base + lane * 16;
      int row = off >> 6;
      int col = off & 63;
      gload16((const char*)A + ((size_t)(bm + row) * K + kb) * 2 + col, (char*)As + base);
    }
    for (int base = wid * 1024; base < BN * 64; base += 4096) {
      int off = base + lane * 16;
      int row = off >> 6;
      int col = off & 63;
      gload16((const char*)BT + ((size_t)(bn + row) * K + kb) * 2 + col, (char*)Bs + base);
    }
    __syncthreads();

    bf16x8 af[TM], bfr[TN];
#pragma unroll
    for (int i = 0; i < TM; ++i)
      af[i] = *(const bf16x8*)&As[(wm * TM * 16 + i * 16 + arow) * BK + koff];
#pragma unroll
    for (int j = 0; j < TN; ++j)
      bfr[j] = *(const bf16x8*)&Bs[(wn * TN * 16 + j * 16 + arow) * BK + koff];
#pragma unroll
    for (int i = 0; i < TM; ++i)
#pragma unroll
      for (int j = 0; j < TN; ++j)
        acc[i][j] = MFMA16x16x32(af[i], bfr[j], acc[i][j]);
    __syncthreads();
  }

  const int m0 = bm + wm * TM * 16 + (lane >> 4) * 4;
  const int n0 = bn + wn * TN * 16 + (lane & 15);
#pragma unroll
  for (int i = 0; i < TM; ++i)
#pragma unroll
    for (int j = 0; j < TN; ++j)
#pragma unroll
      for (int r = 0; r < 4; ++r) {
        int m = m0 + i * 16 + r;
        int n = n0 + j * 16;
        float v = acc[i][j][r];
        if constexpr (OUT_F32)
          ((float*)C)[(size_t)m * N + n] = v;
        else
          ((bf16*)C)[(size_t)m * N + n] = (bf16)v;
      }
}

// ---------------- flash attention v3: causal-balanced q-tile pairs ----------------
// Block handles q-tiles (p, 31-p) of 64 rows each (4 waves, 16 rows/wave) in ONE
// KV sweep: staged K/V tile is shared by both q-tiles. Uniform 33 tile-computes
// per block. Double-buffered LDS, counted vmcnt, XOR swizzle.
// Q: [4096][1024]; KV: [4096][2048] (K cols 0..1023); VT: [(bh)*64+d][2048]; O: [4096][1024].
__global__ __launch_bounds__(256) void mla_attn(const bf16* __restrict__ Q,
                                                const bf16* __restrict__ KV,
                                                const bf16* __restrict__ VT,
                                                bf16* __restrict__ O) {
  const int p = blockIdx.x;           // pair id 0..15
  const int bh = blockIdx.y;
  const int b = bh >> 4, h = bh & 15;
  const int tid = threadIdx.x, lane = tid & 63, w = tid >> 6;
  const int arow = lane & 15;
  const int grp = lane >> 4;
  const int qb_hi = (31 - p) * 64;
  const int qb_lo = p * 64;
  const int nt_hi = 32 - p;
  const int nt_lo = p + 1;

  __shared__ __align__(16) bf16 Ks[2][64 * 64];   // [buf][key][d], swizzled
  __shared__ __align__(16) bf16 Vs[2][64 * 64];   // [buf][d][key], swizzled
  __shared__ __align__(16) bf16 Ps[4][16 * 64];   // per-wave [q][key], swizzled

  // Q fragments (16 rows per wave per q-tile)
  bf16x8 qf_hi[2], qf_lo[2];
  {
    const bf16* qh = Q + ((size_t)(b * 2048 + qb_hi + w * 16 + arow)) * 1024 + h * 64 + grp * 8;
    qf_hi[0] = *(const bf16x8*)qh;
    qf_hi[1] = *(const bf16x8*)(qh + 32);
    const bf16* ql = Q + ((size_t)(b * 2048 + qb_lo + w * 16 + arow)) * 1024 + h * 64 + grp * 8;
    qf_lo[0] = *(const bf16x8*)ql;
    qf_lo[1] = *(const bf16x8*)(ql + 32);
  }
  asm volatile("s_waitcnt vmcnt(0)" ::: "memory");  // drain Q loads for clean vmcnt counting

  auto stage = [&](int buf, int kbase) {
#pragma unroll
    for (int i = 0; i < 2; ++i) {
      const int base = w * 2048 + i * 1024;
      const int dst = base + lane * 16;
      const int row = dst >> 7;
      const int cp = dst & 127;
      const int src_c = cp ^ ((row & 7) << 4);
      gload16((const char*)KV + ((size_t)(b * 2048 + kbase + row) * 2048 + h * 64) * 2 + src_c,
              (char*)&Ks[buf][0] + base);
    }
#pragma unroll
    for (int i = 0; i < 2; ++i) {
      const int base = w * 2048 + i * 1024;
      const int dst = base + lane * 16;
      const int drow = dst >> 7;
      const int cp = dst & 127;
      const int src_c = cp ^ ((drow & 7) << 4);
      gload16((const char*)VT + ((size_t)(bh * 64 + drow) * 2048 + kbase) * 2 + src_c,
              (char*)&Vs[buf][0] + base);
    }
  };

  float m_hi[4], l_hi[4], m_lo[4], l_lo[4];
  f32x4 o_hi[4] = {}, o_lo[4] = {};
#pragma unroll
  for (int r = 0; r < 4; ++r) {
    m_hi[r] = -1e30f; l_hi[r] = 0.f;
    m_lo[r] = -1e30f; l_lo[r] = 0.f;
  }

  // one tile-compute for one q-tile (kf/vf shared between hi and lo)
  auto attend = [&](int qbase, const bf16x8 (&qf)[2], float (&m_r)[4], float (&l_r)[4],
                    f32x4 (&oacc)[4], const bf16x8 (&kf)[4][2], const bf16x8 (&vf)[4][2],
                    int kbase) {
    f32x4 s[4] = {};
#pragma unroll
    for (int kb2 = 0; kb2 < 4; ++kb2)
#pragma unroll
      for (int dc = 0; dc < 2; ++dc)
        s[kb2] = MFMA16x16x32(qf[dc], kf[kb2][dc], s[kb2]);

    const int q0 = qbase + w * 16;
    const int qrow0 = q0 + grp * 4;
    const bool need_mask = (kbase + 63) > q0;
    float pv[4][4];
#pragma unroll
    for (int kb2 = 0; kb2 < 4; ++kb2)
#pragma unroll
      for (int r = 0; r < 4; ++r) {
        float v = s[kb2][r] * 0.18033688011112042f;  // 0.125 * log2(e)
        if (need_mask && (kbase + kb2 * 16 + arow > qrow0 + r)) v = -1e30f;
        pv[kb2][r] = v;
      }
#pragma unroll
    for (int r = 0; r < 4; ++r) {
      float mx = fmaxf(fmaxf(pv[0][r], pv[1][r]), fmaxf(pv[2][r], pv[3][r]));
      mx = fmaxf(mx, __shfl_xor(mx, 1));
      mx = fmaxf(mx, __shfl_xor(mx, 2));
      mx = fmaxf(mx, __shfl_xor(mx, 4));
      mx = fmaxf(mx, __shfl_xor(mx, 8));
      const float mnew = fmaxf(m_r[r], mx);
      const float alpha = exp2f(m_r[r] - mnew);
      m_r[r] = mnew;
      float rs = 0.f;
#pragma unroll
      for (int kb2 = 0; kb2 < 4; ++kb2) {
        const float e = exp2f(pv[kb2][r] - mnew);
        pv[kb2][r] = e;
        rs += e;
      }
      rs += __shfl_xor(rs, 1);
      rs += __shfl_xor(rs, 2);
      rs += __shfl_xor(rs, 4);
      rs += __shfl_xor(rs, 8);
      l_r[r] = l_r[r] * alpha + rs;
#pragma unroll
      for (int db = 0; db < 4; ++db)
        oacc[db][r] *= alpha;
    }
    // P -> per-wave swizzled LDS tile (wave-private: no barrier needed)
#pragma unroll
    for (int kb2 = 0; kb2 < 4; ++kb2)
#pragma unroll
      for (int r = 0; r < 4; ++r) {
        const int prow = grp * 4 + r;
        const int pbyte = prow * 128 + (((kb2 * 16 + arow) * 2) ^ ((prow & 7) << 4));
        *(bf16*)((char*)&Ps[w][0] + pbyte) = (bf16)pv[kb2][r];
      }
    bf16x8 pf[2];
#pragma unroll
    for (int kb = 0; kb < 2; ++kb) {
      const int prow = arow;
      const int pbyte = prow * 128 + ((kb * 64 + grp * 16) ^ ((prow & 7) << 4));
      pf[kb] = *(const bf16x8*)((const char*)&Ps[w][0] + pbyte);
    }
#pragma unroll
    for (int db = 0; db < 4; ++db)
#pragma unroll
      for (int kb = 0; kb < 2; ++kb)
        oacc[db] = MFMA16x16x32(pf[kb], vf[db][kb], oacc[db]);
  };

  stage(0, 0);
  for (int t = 0; t < nt_hi; ++t) {
    const int cur = t & 1;
    const int kbase = t * 64;
    if (t + 1 < nt_hi) {
      stage(cur ^ 1, kbase + 64);
      asm volatile("s_waitcnt vmcnt(4)" ::: "memory");  // buf[cur] ready; prefetch in flight
    } else {
      asm volatile("s_waitcnt vmcnt(0)" ::: "memory");
    }
    __builtin_amdgcn_s_barrier();
    __builtin_amdgcn_sched_barrier(0);

    bf16x8 kf[4][2], vf[4][2];
#pragma unroll
    for (int kb2 = 0; kb2 < 4; ++kb2)
#pragma unroll
      for (int dc = 0; dc < 2; ++dc) {
        const int krow = kb2 * 16 + arow;
        const int kbyte = krow * 128 + ((dc * 64 + grp * 16) ^ ((krow & 7) << 4));
        kf[kb2][dc] = *(const bf16x8*)((const char*)&Ks[cur][0] + kbyte);
      }
#pragma unroll
    for (int db = 0; db < 4; ++db)
#pragma unroll
      for (int kb = 0; kb < 2; ++kb) {
        const int drow = db * 16 + arow;
        const int vbyte = drow * 128 + ((kb * 64 + grp * 16) ^ ((drow & 7) << 4));
        vf[db][kb] = *(const bf16x8*)((const char*)&Vs[cur][0] + vbyte);
      }

    attend(qb_hi, qf_hi, m_hi, l_hi, o_hi, kf, vf, kbase);
    if (t < nt_lo)
      attend(qb_lo, qf_lo, m_lo, l_lo, o_lo, kf, vf, kbase);

    __builtin_amdgcn_sched_barrier(0);
    asm volatile("s_waitcnt lgkmcnt(0)" ::: "memory");
    __builtin_amdgcn_s_barrier();  // all waves done with buf[cur] before overwrite
  }

  // epilogue
#pragma unroll
  for (int r = 0; r < 4; ++r) {
    const float ih = 1.0f / l_hi[r];
    const float il = 1.0f / l_lo[r];
    const int qh = qb_hi + w * 16 + grp * 4 + r;
    const int ql = qb_lo + w * 16 + grp * 4 + r;
#pragma unroll
    for (int db = 0; db < 4; ++db) {
      O[((size_t)(b * 2048 + qh)) * 1024 + h * 64 + db * 16 + arow] = (bf16)(o_hi[db][r] * ih);
      O[((size_t)(b * 2048 + ql)) * 1024 + h * 64 + db * 16 + arow] = (bf16)(o_lo[db][r] * il);
    }
  }
}

// ---------------- host launch ----------------
extern "C" void kernel_launch(void* const* d_in, const int* in_sizes, int n_in,
                              void* d_out, int out_size, void* d_ws, size_t ws_size,
                              hipStream_t stream) {
  const float* x   = (const float*)d_in[0];
  const float* w_c = (const float*)d_in[1];
  const float* w_k = (const float*)d_in[2];
  const float* w_v = (const float*)d_in[3];
  const float* w_q = (const float*)d_in[4];
  const float* w_o = (const float*)d_in[5];
  float* out = (float*)d_out;

  char* ws = (char*)d_ws;
  size_t off = 0;
  auto alloc = [&](size_t bytes) {
    char* p = ws + off;
    off += (bytes + 255) & ~(size_t)255;
    return p;
  };
  bf16* xb      = (bf16*)alloc((size_t)4096 * 1024 * 2);
  bf16* latentb = (bf16*)alloc((size_t)4096 * 64 * 2);
  bf16* KVbuf   = (bf16*)alloc((size_t)4096 * 2048 * 2);  // K cols 0..1023, V cols 1024..2047
  bf16* VTbuf   = (bf16*)alloc((size_t)2048 * 2048 * 2);
  bf16* Qbuf    = (bf16*)alloc((size_t)4096 * 1024 * 2);
  bf16* Obuf    = (bf16*)alloc((size_t)4096 * 1024 * 2);
  bf16* wcT     = (bf16*)alloc((size_t)64 * 1024 * 2);
  bf16* wkvT    = (bf16*)alloc((size_t)2048 * 64 * 2);    // [wkT ; wvT]
  bf16* wqT     = (bf16*)alloc((size_t)1024 * 1024 * 2);
  bf16* woT     = (bf16*)alloc((size_t)1024 * 1024 * 2);

  cvt_f32_bf16<<<4096, 256, 0, stream>>>(x, xb, 1048576);
  transpose_cvt_tiled<<<dim3(1, 16), 256, 0, stream>>>(w_c, wcT, 1024, 64);
  transpose_cvt_tiled<<<dim3(16, 1), 256, 0, stream>>>(w_k, wkvT, 64, 1024);
  transpose_cvt_tiled<<<dim3(16, 1), 256, 0, stream>>>(w_v, wkvT + (size_t)1024 * 64, 64, 1024);
  transpose_cvt_tiled<<<dim3(16, 16), 256, 0, stream>>>(w_q, wqT, 1024, 1024);
  transpose_cvt_tiled<<<dim3(16, 16), 256, 0, stream>>>(w_o, woT, 1024, 1024);

  // latent = x @ w_c : [4096,64]
  gemm_bf16<128, 64, 2, 2, false><<<dim3(32, 1), 256, 0, stream>>>(xb, wcT, latentb, 64, 1024);
  // KV = latent @ [w_k | w_v] : [4096,2048]
  gemm_bf16<128, 128, 2, 2, false><<<dim3(32, 16), 256, 0, stream>>>(latentb, wkvT, KVbuf, 2048, 64);
  transpose_v<<<dim3(32, 16, 2), 256, 0, stream>>>(KVbuf, VTbuf);
  // Q = x @ w_q
  gemm_bf16<128, 128, 2, 2, false><<<dim3(32, 8), 256, 0, stream>>>(xb, wqT, Qbuf, 1024, 1024);
  // attention (16 balanced pairs x 32 bh)
  mla_attn<<<dim3(16, 32), 256, 0, stream>>>(Qbuf, KVbuf, VTbuf, Obuf);
  // out = O @ w_o (fp32 out)
  gemm_bf16<128, 128, 2, 2, true><<<dim3(32, 8), 256, 0, stream>>>(Obuf, woT, (void*)out, 1024, 1024);

  (void)in_sizes; (void)n_in; (void)out_size; (void)ws_size;
}

// Round 4
// 159.016 us; speedup vs baseline: 1.8147x; 1.1717x over previous
//
#include <hip/hip_runtime.h>
#include <hip/hip_bf16.h>
#include <cstdint>
#include <cstddef>

typedef __bf16 bf16;
typedef __attribute__((ext_vector_type(8))) __bf16 bf16x8;
typedef __attribute__((ext_vector_type(4))) __bf16 bf16x4;
typedef __attribute__((ext_vector_type(4))) float f32x4;
typedef __attribute__((ext_vector_type(16))) float f32x16;
typedef __attribute__((ext_vector_type(4))) unsigned int u32x4;

#define MFMA16x16x32(a, b, c) __builtin_amdgcn_mfma_f32_16x16x32_bf16((a), (b), (c), 0, 0, 0)
#define MFMA32x32x16(a, b, c) __builtin_amdgcn_mfma_f32_32x32x16_bf16((a), (b), (c), 0, 0, 0)

__device__ __forceinline__ void gload16(const void* g, void* l) {
  __builtin_amdgcn_global_load_lds((const __attribute__((address_space(1))) unsigned int*)g,
                                   (__attribute__((address_space(3))) unsigned int*)l,
                                   16, 0, 0);
}

__device__ __forceinline__ unsigned packbf(float a, float b) {
  unsigned short ua = __builtin_bit_cast(unsigned short, (bf16)a);
  unsigned short ub = __builtin_bit_cast(unsigned short, (bf16)b);
  return (unsigned)ua | ((unsigned)ub << 16);
}

// ---------------- fp32 -> bf16 convert (x4 vectorized) ----------------
__global__ __launch_bounds__(256) void cvt_f32_bf16(const float* __restrict__ in,
                                                    bf16* __restrict__ out, int n4) {
  int i = blockIdx.x * 256 + threadIdx.x;
  if (i >= n4) return;
  float4 v = reinterpret_cast<const float4*>(in)[i];
  bf16x4 o;
  o[0] = (bf16)v.x; o[1] = (bf16)v.y; o[2] = (bf16)v.z; o[3] = (bf16)v.w;
  *reinterpret_cast<bf16x4*>(out + (size_t)i * 4) = o;
}

// ------------- tiled transpose+convert: in [R][C] f32 -> out [C][R] bf16 -------------
__global__ __launch_bounds__(256) void transpose_cvt_tiled(const float* __restrict__ in,
                                                           bf16* __restrict__ out,
                                                           int R, int C) {
  __shared__ __align__(16) bf16 tile[64][72];
  const int c0 = blockIdx.x * 64, r0 = blockIdx.y * 64;
  const int tid = threadIdx.x;
  {
    int rr = tid >> 4;
    int cc = (tid & 15) * 4;
#pragma unroll
    for (int p = 0; p < 4; ++p) {
      float4 v = *(const float4*)&in[(size_t)(r0 + rr + 16 * p) * C + c0 + cc];
      bf16x4 o;
      o[0] = (bf16)v.x; o[1] = (bf16)v.y; o[2] = (bf16)v.z; o[3] = (bf16)v.w;
      *(bf16x4*)&tile[rr + 16 * p][cc] = o;
    }
  }
  __syncthreads();
  {
    int cc = tid >> 3;
    int rr = (tid & 7) * 8;
#pragma unroll
    for (int p = 0; p < 2; ++p) {
      bf16x8 v;
#pragma unroll
      for (int j = 0; j < 8; ++j) v[j] = tile[rr + j][cc + 32 * p];
      *(bf16x8*)&out[(size_t)(c0 + cc + 32 * p) * R + r0 + rr] = v;
    }
  }
}

// ------------- W_qlatT prep: OUT[h*64+ld][dm] = scale * sum_dh w_q[dm][h64+dh] * w_k[ld][h64+dh] -------------
__global__ __launch_bounds__(256) void prep_wqlat(const float* __restrict__ wq,
                                                  const float* __restrict__ wk,
                                                  bf16* __restrict__ outT) {
  __shared__ float Aq[64][65];
  __shared__ float Ak[64][65];
  const int h = blockIdx.y, dm0 = blockIdx.x * 64;
  const int t = threadIdx.x;
  {
    int row = t >> 2, c0 = (t & 3) * 16;
#pragma unroll
    for (int j = 0; j < 4; ++j) {
      float4 vq = *(const float4*)&wq[(size_t)(dm0 + row) * 1024 + h * 64 + c0 + 4 * j];
      Aq[row][c0 + 4 * j + 0] = vq.x; Aq[row][c0 + 4 * j + 1] = vq.y;
      Aq[row][c0 + 4 * j + 2] = vq.z; Aq[row][c0 + 4 * j + 3] = vq.w;
      float4 vk = *(const float4*)&wk[(size_t)row * 1024 + h * 64 + c0 + 4 * j];
      Ak[row][c0 + 4 * j + 0] = vk.x; Ak[row][c0 + 4 * j + 1] = vk.y;
      Ak[row][c0 + 4 * j + 2] = vk.z; Ak[row][c0 + 4 * j + 3] = vk.w;
    }
  }
  __syncthreads();
  const int ld0 = (t >> 4) * 4, dmq = (t & 15) * 4;
  float acc[4][4] = {};
  for (int dh = 0; dh < 64; ++dh) {
    float rk[4], rq[4];
#pragma unroll
    for (int i = 0; i < 4; ++i) rk[i] = Ak[ld0 + i][dh];
#pragma unroll
    for (int j = 0; j < 4; ++j) rq[j] = Aq[dmq + j][dh];
#pragma unroll
    for (int i = 0; i < 4; ++i)
#pragma unroll
      for (int j = 0; j < 4; ++j) acc[i][j] += rk[i] * rq[j];
  }
  const float S = 0.18033688011112042f;  // 1/sqrt(64) * log2(e), folded into q_lat
#pragma unroll
  for (int i = 0; i < 4; ++i) {
    bf16x4 o;
#pragma unroll
    for (int j = 0; j < 4; ++j) o[j] = (bf16)(acc[i][j] * S);
    *(bf16x4*)&outT[(size_t)(h * 64 + ld0 + i) * 1024 + dm0 + dmq] = o;
  }
}

// ------------- W_outT prep: OUT[dn][h*64+lv] = sum_dh w_v[lv][h64+dh] * w_o[h64+dh][dn] -------------
__global__ __launch_bounds__(256) void prep_wout(const float* __restrict__ wv,
                                                 const float* __restrict__ wo,
                                                 bf16* __restrict__ outT) {
  __shared__ float Av[64][65];
  __shared__ float Ao[64][65];
  const int h = blockIdx.y, dn0 = blockIdx.x * 64;
  const int t = threadIdx.x;
  {
    int row = t >> 2, c0 = (t & 3) * 16;
#pragma unroll
    for (int j = 0; j < 4; ++j) {
      float4 vv = *(const float4*)&wv[(size_t)row * 1024 + h * 64 + c0 + 4 * j];
      Av[row][c0 + 4 * j + 0] = vv.x; Av[row][c0 + 4 * j + 1] = vv.y;
      Av[row][c0 + 4 * j + 2] = vv.z; Av[row][c0 + 4 * j + 3] = vv.w;
      float4 vo = *(const float4*)&wo[(size_t)(h * 64 + row) * 1024 + dn0 + c0 + 4 * j];
      Ao[row][c0 + 4 * j + 0] = vo.x; Ao[row][c0 + 4 * j + 1] = vo.y;
      Ao[row][c0 + 4 * j + 2] = vo.z; Ao[row][c0 + 4 * j + 3] = vo.w;
    }
  }
  __syncthreads();
  const int dnq = (t >> 4) * 4, lv0 = (t & 15) * 4;
  float acc[4][4] = {};
  for (int dh = 0; dh < 64; ++dh) {
    float ro[4], rv[4];
#pragma unroll
    for (int i = 0; i < 4; ++i) ro[i] = Ao[dh][dnq + i];
#pragma unroll
    for (int j = 0; j < 4; ++j) rv[j] = Av[lv0 + j][dh];
#pragma unroll
    for (int i = 0; i < 4; ++i)
#pragma unroll
      for (int j = 0; j < 4; ++j) acc[i][j] += ro[i] * rv[j];
  }
#pragma unroll
  for (int i = 0; i < 4; ++i) {
    bf16x4 o;
#pragma unroll
    for (int j = 0; j < 4; ++j) o[j] = (bf16)acc[i][j];
    *(bf16x4*)&outT[(size_t)(dn0 + dnq + i) * 1024 + h * 64 + lv0] = o;
  }
}

// ------------- latent reduce (8 K-slices) + cvt + transpose: latpart [8][4096][64] f32 -> latent bf16, latT bf16 -------------
__global__ __launch_bounds__(256) void cvt_lat(const float* __restrict__ part,
                                               bf16* __restrict__ latent,
                                               bf16* __restrict__ latT) {
  __shared__ __align__(16) bf16 tile[64][72];
  const int r0 = blockIdx.x * 64;
  const int t = threadIdx.x;
  {
    int row = t >> 2, c0 = (t & 3) * 16;
    float acc[16] = {};
#pragma unroll
    for (int z = 0; z < 8; ++z) {
      const float* p = part + (size_t)z * 4096 * 64 + (size_t)(r0 + row) * 64 + c0;
#pragma unroll
      for (int j = 0; j < 4; ++j) {
        float4 v = *(const float4*)(p + 4 * j);
        acc[4 * j + 0] += v.x; acc[4 * j + 1] += v.y;
        acc[4 * j + 2] += v.z; acc[4 * j + 3] += v.w;
      }
    }
#pragma unroll
    for (int j = 0; j < 4; ++j) {
      bf16x4 o;
#pragma unroll
      for (int k = 0; k < 4; ++k) o[k] = (bf16)acc[4 * j + k];
      *(bf16x4*)&latent[(size_t)(r0 + row) * 64 + c0 + 4 * j] = o;
      *(bf16x4*)&tile[row][c0 + 4 * j] = o;
    }
  }
  __syncthreads();
  {
    int ld = t >> 2, tc = (t & 3) * 16;
#pragma unroll
    for (int p2 = 0; p2 < 2; ++p2) {
      bf16x8 v;
#pragma unroll
      for (int j = 0; j < 8; ++j) v[j] = tile[tc + p2 * 8 + j][ld];
      *(bf16x8*)&latT[(size_t)ld * 4096 + r0 + tc + p2 * 8] = v;
    }
  }
}

// ---------------- bf16 MFMA GEMM: C[M,N] = A[M,K-slice] * BT[N,K-slice]^T ----------------
// klen: K-range per blockIdx.z slice; czoff: C element offset per z (for K-split partials).
template <int BM, int BN, int WM, int WN, bool OUT_F32>
__global__ __launch_bounds__(256) void gemm_bf16(const bf16* __restrict__ A,
                                                 const bf16* __restrict__ BT,
                                                 void* __restrict__ C,
                                                 int N, int klen, size_t czoff) {
  constexpr int BK = 32;
  constexpr int TM = (BM / WM) / 16;
  constexpr int TN = (BN / WN) / 16;
  __shared__ __align__(16) bf16 As[BM * BK];
  __shared__ __align__(16) bf16 Bs[BN * BK];
  const int tid = threadIdx.x;
  const int lane = tid & 63;
  const int wid = tid >> 6;
  const int wm = wid / WN;
  const int wn = wid % WN;
  const int bm = blockIdx.x * BM;
  const int bn = blockIdx.y * BN;
  const int K = klen * gridDim.z;  // full K for row strides
  const int kbeg = blockIdx.z * klen;
  const int arow = lane & 15;
  const int koff = (lane >> 4) * 8;

  f32x4 acc[TM][TN] = {};

  for (int kb = kbeg; kb < kbeg + klen; kb += BK) {
    for (int base = wid * 1024; base < BM * 64; base += 4096) {
      int off = base + lane * 16;
      int row = off >> 6;
      int col = off & 63;
      gload16((const char*)A + ((size_t)(bm + row) * K + kb) * 2 + col, (char*)As + base);
    }
    for (int base = wid * 1024; base < BN * 64; base += 4096) {
      int off = base + lane * 16;
      int row = off >> 6;
      int col = off & 63;
      gload16((const char*)BT + ((size_t)(bn + row) * K + kb) * 2 + col, (char*)Bs + base);
    }
    __syncthreads();

    bf16x8 af[TM], bfr[TN];
#pragma unroll
    for (int i = 0; i < TM; ++i)
      af[i] = *(const bf16x8*)&As[(wm * TM * 16 + i * 16 + arow) * BK + koff];
#pragma unroll
    for (int j = 0; j < TN; ++j)
      bfr[j] = *(const bf16x8*)&Bs[(wn * TN * 16 + j * 16 + arow) * BK + koff];
#pragma unroll
    for (int i = 0; i < TM; ++i)
#pragma unroll
      for (int j = 0; j < TN; ++j)
        acc[i][j] = MFMA16x16x32(af[i], bfr[j], acc[i][j]);
    __syncthreads();
  }

  const int m0 = bm + wm * TM * 16 + (lane >> 4) * 4;
  const int n0 = bn + wn * TN * 16 + (lane & 15);
#pragma unroll
  for (int i = 0; i < TM; ++i)
#pragma unroll
    for (int j = 0; j < TN; ++j)
#pragma unroll
      for (int r = 0; r < 4; ++r) {
        int m = m0 + i * 16 + r;
        int n = n0 + j * 16;
        float v = acc[i][j][r];
        if constexpr (OUT_F32)
          ((float*)C + czoff * blockIdx.z)[(size_t)m * N + n] = v;
        else
          ((bf16*)C)[(size_t)m * N + n] = (bf16)v;
      }
}

// ---------------- absorbed flash attention: barrier-free, per-wave jobs ----------------
// S = q_lat_h @ latent^T (scale pre-folded, log2 units); out_lat_h = P @ latent.
// Swapped QK^T (32x32x16): lane owns q = lane&31; P repack in registers; O^T accum.
// Wave job = (pair, b, h): hi chunk (63-pair)*32 rows (64-pair KV tiles) + lo chunk pair*32 rows (pair+1 tiles).
__global__ __launch_bounds__(256) void mla_attn2(const bf16* __restrict__ q_lat,
                                                 const bf16* __restrict__ lat,
                                                 const bf16* __restrict__ latT,
                                                 bf16* __restrict__ out_lat) {
  __shared__ __align__(16) bf16 etile[4][32][72];
  const int tid = threadIdx.x, lane = tid & 63, w = tid >> 6;
  const int jid = blockIdx.x * 4 + w;
  const int pair = jid & 31;
  const int bh = jid >> 5;
  const int b = bh >> 4, h = bh & 15;
  const int li = lane & 31;
  const int hb = lane >> 5;
  const size_t boff = (size_t)b * 2048;

  auto loadK = [&](bf16x8 (&ka)[4], int kb) {
    const bf16* base = lat + ((size_t)(boff + kb + li)) * 64 + hb * 8;
#pragma unroll
    for (int s = 0; s < 4; ++s) ka[s] = *(const bf16x8*)(base + 16 * s);
  };
  auto loadV = [&](bf16x8 (&va)[2][2], int kb) {
#pragma unroll
    for (int ldb = 0; ldb < 2; ++ldb) {
      const bf16* base = latT + (size_t)(32 * ldb + li) * 4096 + boff + kb + hb * 8;
#pragma unroll
      for (int s2 = 0; s2 < 2; ++s2) va[ldb][s2] = *(const bf16x8*)(base + 16 * s2);
    }
  };

  for (int chunk = 0; chunk < 2; ++chunk) {
    const int q0 = (chunk == 0 ? (63 - pair) : pair) * 32;
    const int nt = (chunk == 0 ? 64 - pair : pair + 1);

    bf16x8 qf[4];
    {
      const bf16* qp = q_lat + ((size_t)(boff + q0 + li)) * 1024 + h * 64 + hb * 8;
#pragma unroll
      for (int s = 0; s < 4; ++s) qf[s] = *(const bf16x8*)(qp + 16 * s);
    }

    float m_r = -3e38f, lsum = 0.f;
    f32x16 ot0 = {}, ot1 = {};

    auto tilecompute = [&](const bf16x8 (&ka)[4], const bf16x8 (&va)[2][2], int t) {
      f32x16 st = {};
#pragma unroll
      for (int s = 0; s < 4; ++s) st = MFMA32x32x16(ka[s], qf[s], st);
      float p[16];
#pragma unroll
      for (int r = 0; r < 16; ++r) p[r] = st[r];
      if (t == nt - 1) {  // diagonal tile mask: k_local > q_local
#pragma unroll
        for (int r = 0; r < 16; ++r) {
          const int krow = (r & 3) + 8 * (r >> 2) + 4 * hb;
          if (krow > li) p[r] = -1e30f;
        }
      }
      float mx = p[0];
#pragma unroll
      for (int r = 1; r < 16; ++r) mx = fmaxf(mx, p[r]);
      mx = fmaxf(mx, __shfl_xor(mx, 32));
      const float mnew = fmaxf(m_r, mx);
      const float alpha = exp2f(m_r - mnew);
      m_r = mnew;
      float rs = 0.f;
#pragma unroll
      for (int r = 0; r < 16; ++r) {
        p[r] = exp2f(p[r] - mnew);
        rs += p[r];
      }
      rs += __shfl_xor(rs, 32);
      lsum = lsum * alpha + rs;
#pragma unroll
      for (int r = 0; r < 16; ++r) { ot0[r] *= alpha; ot1[r] *= alpha; }
      // P^T B-fragments: slot j of half hb <-> k = 8*hb + j (+16 for frag2).
      const unsigned A0 = packbf(p[0], p[1]), A1 = packbf(p[2], p[3]);
      const unsigned B0 = packbf(p[4], p[5]), B1 = packbf(p[6], p[7]);
      const unsigned C0 = packbf(p[8], p[9]), C1 = packbf(p[10], p[11]);
      const unsigned D0 = packbf(p[12], p[13]), D1 = packbf(p[14], p[15]);
      const unsigned sA0 = (unsigned)__shfl_xor((int)A0, 32), sA1 = (unsigned)__shfl_xor((int)A1, 32);
      const unsigned sB0 = (unsigned)__shfl_xor((int)B0, 32), sB1 = (unsigned)__shfl_xor((int)B1, 32);
      const unsigned sC0 = (unsigned)__shfl_xor((int)C0, 32), sC1 = (unsigned)__shfl_xor((int)C1, 32);
      const unsigned sD0 = (unsigned)__shfl_xor((int)D0, 32), sD1 = (unsigned)__shfl_xor((int)D1, 32);
      u32x4 w1 = hb ? (u32x4){sB0, sB1, B0, B1} : (u32x4){A0, A1, sA0, sA1};
      u32x4 w2 = hb ? (u32x4){sD0, sD1, D0, D1} : (u32x4){C0, C1, sC0, sC1};
      const bf16x8 pb1 = __builtin_bit_cast(bf16x8, w1);
      const bf16x8 pb2 = __builtin_bit_cast(bf16x8, w2);
      ot0 = MFMA32x32x16(va[0][0], pb1, ot0);
      ot0 = MFMA32x32x16(va[0][1], pb2, ot0);
      ot1 = MFMA32x32x16(va[1][0], pb1, ot1);
      ot1 = MFMA32x32x16(va[1][1], pb2, ot1);
    };

    bf16x8 kaA[4], vaA[2][2], kaB[4], vaB[2][2];
    loadK(kaA, 0);
    loadV(vaA, 0);
    int t = 0;
    while (true) {
      if (t + 1 < nt) { loadK(kaB, (t + 1) * 32); loadV(vaB, (t + 1) * 32); }
      tilecompute(kaA, vaA, t);
      ++t;
      if (t == nt) break;
      if (t + 1 < nt) { loadK(kaA, (t + 1) * 32); loadV(vaA, (t + 1) * 32); }
      tilecompute(kaB, vaB, t);
      ++t;
      if (t == nt) break;
    }

    // epilogue: OT (lane q=li, regs ld=crow+32*ldb) -> LDS transpose -> coalesced store
    const float inv = 1.0f / lsum;
#pragma unroll
    for (int r = 0; r < 16; ++r) {
      const int ldr = (r & 3) + 8 * (r >> 2) + 4 * hb;
      etile[w][li][ldr] = (bf16)(ot0[r] * inv);
      etile[w][li][ldr + 32] = (bf16)(ot1[r] * inv);
    }
    asm volatile("s_waitcnt lgkmcnt(0)" ::: "memory");
    __builtin_amdgcn_sched_barrier(0);
    {
      bf16* op = out_lat + ((size_t)(boff + q0 + li)) * 1024 + h * 64 + hb * 32;
#pragma unroll
      for (int j = 0; j < 4; ++j)
        *(bf16x8*)(op + 8 * j) = *(const bf16x8*)&etile[w][li][hb * 32 + 8 * j];
    }
    asm volatile("s_waitcnt lgkmcnt(0)" ::: "memory");  // etile reuse safety across chunks
    __builtin_amdgcn_sched_barrier(0);
  }
}

// ---------------- host launch ----------------
extern "C" void kernel_launch(void* const* d_in, const int* in_sizes, int n_in,
                              void* d_out, int out_size, void* d_ws, size_t ws_size,
                              hipStream_t stream) {
  const float* x   = (const float*)d_in[0];
  const float* w_c = (const float*)d_in[1];
  const float* w_k = (const float*)d_in[2];
  const float* w_v = (const float*)d_in[3];
  const float* w_q = (const float*)d_in[4];
  const float* w_o = (const float*)d_in[5];
  float* out = (float*)d_out;

  char* ws = (char*)d_ws;
  size_t off = 0;
  auto alloc = [&](size_t bytes) {
    char* p = ws + off;
    off += (bytes + 255) & ~(size_t)255;
    return p;
  };
  bf16*  xb      = (bf16*)alloc((size_t)4096 * 1024 * 2);
  float* latpart = (float*)alloc((size_t)8 * 4096 * 64 * 4);
  bf16*  latent  = (bf16*)alloc((size_t)4096 * 64 * 2);
  bf16*  latT    = (bf16*)alloc((size_t)64 * 4096 * 2);
  bf16*  qlat    = (bf16*)alloc((size_t)4096 * 1024 * 2);
  bf16*  outlat  = (bf16*)alloc((size_t)4096 * 1024 * 2);
  bf16*  wcT     = (bf16*)alloc((size_t)64 * 1024 * 2);
  bf16*  WqlatT  = (bf16*)alloc((size_t)1024 * 1024 * 2);
  bf16*  WoutT   = (bf16*)alloc((size_t)1024 * 1024 * 2);

  cvt_f32_bf16<<<4096, 256, 0, stream>>>(x, xb, 1048576);
  transpose_cvt_tiled<<<dim3(1, 16), 256, 0, stream>>>(w_c, wcT, 1024, 64);
  prep_wqlat<<<dim3(16, 16), 256, 0, stream>>>(w_q, w_k, WqlatT);
  prep_wout<<<dim3(16, 16), 256, 0, stream>>>(w_v, w_o, WoutT);

  // latent partials: K split 8 ways -> [8][4096][64] f32
  gemm_bf16<128, 64, 2, 2, true><<<dim3(32, 1, 8), 256, 0, stream>>>(
      xb, wcT, latpart, 64, 128, (size_t)4096 * 64);
  cvt_lat<<<64, 256, 0, stream>>>(latpart, latent, latT);

  // q_lat = xb @ W_qlatT  (scale folded)
  gemm_bf16<128, 128, 2, 2, false><<<dim3(32, 8), 256, 0, stream>>>(
      xb, WqlatT, qlat, 1024, 1024, 0);

  // attention: 1024 wave-jobs, 4 waves/block
  mla_attn2<<<256, 256, 0, stream>>>(qlat, latent, latT, outlat);

  // out = out_lat @ W_outT (fp32)
  gemm_bf16<128, 128, 2, 2, true><<<dim3(32, 8), 256, 0, stream>>>(
      outlat, WoutT, (void*)out, 1024, 1024, 0);

  (void)in_sizes; (void)n_in; (void)out_size; (void)ws_size;
}

// Round 6
// 145.902 us; speedup vs baseline: 1.9778x; 1.0899x over previous
//
#include <hip/hip_runtime.h>
#include <hip/hip_bf16.h>
#include <cstdint>
#include <cstddef>

typedef __bf16 bf16;
typedef __attribute__((ext_vector_type(8))) __bf16 bf16x8;
typedef __attribute__((ext_vector_type(4))) __bf16 bf16x4;
typedef __attribute__((ext_vector_type(4))) float f32x4;
typedef __attribute__((ext_vector_type(16))) float f32x16;
typedef __attribute__((ext_vector_type(4))) unsigned int u32x4;

#define MFMA16x16x32(a, b, c) __builtin_amdgcn_mfma_f32_16x16x32_bf16((a), (b), (c), 0, 0, 0)
#define MFMA32x32x16(a, b, c) __builtin_amdgcn_mfma_f32_32x32x16_bf16((a), (b), (c), 0, 0, 0)

__device__ __forceinline__ void gload16(const void* g, void* l) {
  __builtin_amdgcn_global_load_lds((const __attribute__((address_space(1))) unsigned int*)g,
                                   (__attribute__((address_space(3))) unsigned int*)l,
                                   16, 0, 0);
}

__device__ __forceinline__ unsigned packbf(float a, float b) {
  unsigned short ua = __builtin_bit_cast(unsigned short, (bf16)a);
  unsigned short ub = __builtin_bit_cast(unsigned short, (bf16)b);
  return (unsigned)ua | ((unsigned)ub << 16);
}

// ---------------- fp32 -> bf16 convert (x4 vectorized) ----------------
__global__ __launch_bounds__(256) void cvt_f32_bf16(const float* __restrict__ in,
                                                    bf16* __restrict__ out, int n4) {
  int i = blockIdx.x * 256 + threadIdx.x;
  if (i >= n4) return;
  float4 v = reinterpret_cast<const float4*>(in)[i];
  bf16x4 o;
  o[0] = (bf16)v.x; o[1] = (bf16)v.y; o[2] = (bf16)v.z; o[3] = (bf16)v.w;
  *reinterpret_cast<bf16x4*>(out + (size_t)i * 4) = o;
}

// ------------- tiled transpose+convert: in [R][C] f32 -> out [C][R] bf16 -------------
__global__ __launch_bounds__(256) void transpose_cvt_tiled(const float* __restrict__ in,
                                                           bf16* __restrict__ out,
                                                           int R, int C) {
  __shared__ __align__(16) bf16 tile[64][72];
  const int c0 = blockIdx.x * 64, r0 = blockIdx.y * 64;
  const int tid = threadIdx.x;
  {
    int rr = tid >> 4;
    int cc = (tid & 15) * 4;
#pragma unroll
    for (int p = 0; p < 4; ++p) {
      float4 v = *(const float4*)&in[(size_t)(r0 + rr + 16 * p) * C + c0 + cc];
      bf16x4 o;
      o[0] = (bf16)v.x; o[1] = (bf16)v.y; o[2] = (bf16)v.z; o[3] = (bf16)v.w;
      *(bf16x4*)&tile[rr + 16 * p][cc] = o;
    }
  }
  __syncthreads();
  {
    int cc = tid >> 3;
    int rr = (tid & 7) * 8;
#pragma unroll
    for (int p = 0; p < 2; ++p) {
      bf16x8 v;
#pragma unroll
      for (int j = 0; j < 8; ++j) v[j] = tile[rr + j][cc + 32 * p];
      *(bf16x8*)&out[(size_t)(c0 + cc + 32 * p) * R + r0 + rr] = v;
    }
  }
}

// ------------- W_qlatT prep: OUT[h*64+ld][dm] = scale * sum_dh w_q[dm][h64+dh] * w_k[ld][h64+dh] -------------
__global__ __launch_bounds__(256) void prep_wqlat(const float* __restrict__ wq,
                                                  const float* __restrict__ wk,
                                                  bf16* __restrict__ outT) {
  __shared__ float Aq[64][65];
  __shared__ float Ak[64][65];
  const int h = blockIdx.y, dm0 = blockIdx.x * 64;
  const int t = threadIdx.x;
  {
    int row = t >> 2, c0 = (t & 3) * 16;
#pragma unroll
    for (int j = 0; j < 4; ++j) {
      float4 vq = *(const float4*)&wq[(size_t)(dm0 + row) * 1024 + h * 64 + c0 + 4 * j];
      Aq[row][c0 + 4 * j + 0] = vq.x; Aq[row][c0 + 4 * j + 1] = vq.y;
      Aq[row][c0 + 4 * j + 2] = vq.z; Aq[row][c0 + 4 * j + 3] = vq.w;
      float4 vk = *(const float4*)&wk[(size_t)row * 1024 + h * 64 + c0 + 4 * j];
      Ak[row][c0 + 4 * j + 0] = vk.x; Ak[row][c0 + 4 * j + 1] = vk.y;
      Ak[row][c0 + 4 * j + 2] = vk.z; Ak[row][c0 + 4 * j + 3] = vk.w;
    }
  }
  __syncthreads();
  const int ld0 = (t >> 4) * 4, dmq = (t & 15) * 4;
  float acc[4][4] = {};
  for (int dh = 0; dh < 64; ++dh) {
    float rk[4], rq[4];
#pragma unroll
    for (int i = 0; i < 4; ++i) rk[i] = Ak[ld0 + i][dh];
#pragma unroll
    for (int j = 0; j < 4; ++j) rq[j] = Aq[dmq + j][dh];
#pragma unroll
    for (int i = 0; i < 4; ++i)
#pragma unroll
      for (int j = 0; j < 4; ++j) acc[i][j] += rk[i] * rq[j];
  }
  const float S = 0.18033688011112042f;  // 1/sqrt(64) * log2(e), folded into q_lat
#pragma unroll
  for (int i = 0; i < 4; ++i) {
    bf16x4 o;
#pragma unroll
    for (int j = 0; j < 4; ++j) o[j] = (bf16)(acc[i][j] * S);
    *(bf16x4*)&outT[(size_t)(h * 64 + ld0 + i) * 1024 + dm0 + dmq] = o;
  }
}

// ------------- W_outT prep: OUT[dn][h*64+lv] = sum_dh w_v[lv][h64+dh] * w_o[h64+dh][dn] -------------
__global__ __launch_bounds__(256) void prep_wout(const float* __restrict__ wv,
                                                 const float* __restrict__ wo,
                                                 bf16* __restrict__ outT) {
  __shared__ float Av[64][65];
  __shared__ float Ao[64][65];
  const int h = blockIdx.y, dn0 = blockIdx.x * 64;
  const int t = threadIdx.x;
  {
    int row = t >> 2, c0 = (t & 3) * 16;
#pragma unroll
    for (int j = 0; j < 4; ++j) {
      float4 vv = *(const float4*)&wv[(size_t)row * 1024 + h * 64 + c0 + 4 * j];
      Av[row][c0 + 4 * j + 0] = vv.x; Av[row][c0 + 4 * j + 1] = vv.y;
      Av[row][c0 + 4 * j + 2] = vv.z; Av[row][c0 + 4 * j + 3] = vv.w;
      float4 vo = *(const float4*)&wo[(size_t)(h * 64 + row) * 1024 + dn0 + c0 + 4 * j];
      Ao[row][c0 + 4 * j + 0] = vo.x; Ao[row][c0 + 4 * j + 1] = vo.y;
      Ao[row][c0 + 4 * j + 2] = vo.z; Ao[row][c0 + 4 * j + 3] = vo.w;
    }
  }
  __syncthreads();
  const int dnq = (t >> 4) * 4, lv0 = (t & 15) * 4;
  float acc[4][4] = {};
  for (int dh = 0; dh < 64; ++dh) {
    float ro[4], rv[4];
#pragma unroll
    for (int i = 0; i < 4; ++i) ro[i] = Ao[dh][dnq + i];
#pragma unroll
    for (int j = 0; j < 4; ++j) rv[j] = Av[lv0 + j][dh];
#pragma unroll
    for (int i = 0; i < 4; ++i)
#pragma unroll
      for (int j = 0; j < 4; ++j) acc[i][j] += ro[i] * rv[j];
  }
#pragma unroll
  for (int i = 0; i < 4; ++i) {
    bf16x4 o;
#pragma unroll
    for (int j = 0; j < 4; ++j) o[j] = (bf16)acc[i][j];
    *(bf16x4*)&outT[(size_t)(dn0 + dnq + i) * 1024 + h * 64 + lv0] = o;
  }
}

// ------------- latent reduce (8 K-slices) + cvt + transpose -------------
__global__ __launch_bounds__(256) void cvt_lat(const float* __restrict__ part,
                                               bf16* __restrict__ latent,
                                               bf16* __restrict__ latT) {
  __shared__ __align__(16) bf16 tile[64][72];
  const int r0 = blockIdx.x * 64;
  const int t = threadIdx.x;
  {
    int row = t >> 2, c0 = (t & 3) * 16;
    float acc[16] = {};
#pragma unroll
    for (int z = 0; z < 8; ++z) {
      const float* p = part + (size_t)z * 4096 * 64 + (size_t)(r0 + row) * 64 + c0;
#pragma unroll
      for (int j = 0; j < 4; ++j) {
        float4 v = *(const float4*)(p + 4 * j);
        acc[4 * j + 0] += v.x; acc[4 * j + 1] += v.y;
        acc[4 * j + 2] += v.z; acc[4 * j + 3] += v.w;
      }
    }
#pragma unroll
    for (int j = 0; j < 4; ++j) {
      bf16x4 o;
#pragma unroll
      for (int k = 0; k < 4; ++k) o[k] = (bf16)acc[4 * j + k];
      *(bf16x4*)&latent[(size_t)(r0 + row) * 64 + c0 + 4 * j] = o;
      *(bf16x4*)&tile[row][c0 + 4 * j] = o;
    }
  }
  __syncthreads();
  {
    int ld = t >> 2, tc = (t & 3) * 16;
#pragma unroll
    for (int p2 = 0; p2 < 2; ++p2) {
      bf16x8 v;
#pragma unroll
      for (int j = 0; j < 8; ++j) v[j] = tile[tc + p2 * 8 + j][ld];
      *(bf16x8*)&latT[(size_t)ld * 4096 + r0 + tc + p2 * 8] = v;
    }
  }
}

// ---------------- bf16 MFMA GEMM: C[M,N] = A[M,K-slice] * BT[N,K-slice]^T ----------------
template <int BM, int BN, int WM, int WN, bool OUT_F32>
__global__ __launch_bounds__(256) void gemm_bf16(const bf16* __restrict__ A,
                                                 const bf16* __restrict__ BT,
                                                 void* __restrict__ C,
                                                 int N, int klen, size_t czoff) {
  constexpr int BK = 32;
  constexpr int TM = (BM / WM) / 16;
  constexpr int TN = (BN / WN) / 16;
  __shared__ __align__(16) bf16 As[BM * BK];
  __shared__ __align__(16) bf16 Bs[BN * BK];
  const int tid = threadIdx.x;
  const int lane = tid & 63;
  const int wid = tid >> 6;
  const int wm = wid / WN;
  const int wn = wid % WN;
  const int bm = blockIdx.x * BM;
  const int bn = blockIdx.y * BN;
  const int K = klen * gridDim.z;
  const int kbeg = blockIdx.z * klen;
  const int arow = lane & 15;
  const int koff = (lane >> 4) * 8;

  f32x4 acc[TM][TN] = {};

  for (int kb = kbeg; kb < kbeg + klen; kb += BK) {
    for (int base = wid * 1024; base < BM * 64; base += 4096) {
      int off = base + lane * 16;
      int row = off >> 6;
      int col = off & 63;
      gload16((const char*)A + ((size_t)(bm + row) * K + kb) * 2 + col, (char*)As + base);
    }
    for (int base = wid * 1024; base < BN * 64; base += 4096) {
      int off = base + lane * 16;
      int row = off >> 6;
      int col = off & 63;
      gload16((const char*)BT + ((size_t)(bn + row) * K + kb) * 2 + col, (char*)Bs + base);
    }
    __syncthreads();

    bf16x8 af[TM], bfr[TN];
#pragma unroll
    for (int i = 0; i < TM; ++i)
      af[i] = *(const bf16x8*)&As[(wm * TM * 16 + i * 16 + arow) * BK + koff];
#pragma unroll
    for (int j = 0; j < TN; ++j)
      bfr[j] = *(const bf16x8*)&Bs[(wn * TN * 16 + j * 16 + arow) * BK + koff];
#pragma unroll
    for (int i = 0; i < TM; ++i)
#pragma unroll
      for (int j = 0; j < TN; ++j)
        acc[i][j] = MFMA16x16x32(af[i], bfr[j], acc[i][j]);
    __syncthreads();
  }

  const int m0 = bm + wm * TM * 16 + (lane >> 4) * 4;
  const int n0 = bn + wn * TN * 16 + (lane & 15);
#pragma unroll
  for (int i = 0; i < TM; ++i)
#pragma unroll
    for (int j = 0; j < TN; ++j)
#pragma unroll
      for (int r = 0; r < 4; ++r) {
        int m = m0 + i * 16 + r;
        int n = n0 + j * 16;
        float v = acc[i][j][r];
        if constexpr (OUT_F32)
          ((float*)C + czoff * blockIdx.z)[(size_t)m * N + n] = v;
        else
          ((bf16*)C)[(size_t)m * N + n] = (bf16)v;
      }
}

// ---------------- absorbed flash attention v3: one 32-row q-chunk per wave ----------------
// Block = 4 waves = chunks {p, 63-p} x 2 adjacent heads (same b). 512 blocks -> 2/CU, 2 waves/SIMD.
// Swapped QK^T (32x32x16); shfl_xor(32) exchanges (R4-verified); defer-max (THR=8, log2 units).
__global__ __launch_bounds__(256) void mla_attn2(const bf16* __restrict__ q_lat,
                                                 const bf16* __restrict__ lat,
                                                 const bf16* __restrict__ latT,
                                                 bf16* __restrict__ out_lat) {
  __shared__ __align__(16) bf16 etile[4][32][72];
  const int tid = threadIdx.x, lane = tid & 63, w = tid >> 6;
  const int pairp = blockIdx.x & 31;
  const int bhp = blockIdx.x >> 5;   // 0..15
  const int b = bhp >> 3;
  const int h = (bhp & 7) * 2 + (w >> 1);
  const int c = (w & 1) ? pairp : (63 - pairp);
  const int nt = c + 1;
  const int q0 = c * 32;
  const int li = lane & 31;
  const int hb = lane >> 5;
  const size_t boff = (size_t)b * 2048;

  auto loadK = [&](bf16x8 (&ka)[4], int kb) {
    const bf16* base = lat + ((size_t)(boff + kb + li)) * 64 + hb * 8;
#pragma unroll
    for (int s = 0; s < 4; ++s) ka[s] = *(const bf16x8*)(base + 16 * s);
  };
  auto loadV = [&](bf16x8 (&va)[2][2], int kb) {
#pragma unroll
    for (int ldb = 0; ldb < 2; ++ldb) {
      const bf16* base = latT + (size_t)(32 * ldb + li) * 4096 + boff + kb + hb * 8;
#pragma unroll
      for (int s2 = 0; s2 < 2; ++s2) va[ldb][s2] = *(const bf16x8*)(base + 16 * s2);
    }
  };

  bf16x8 qf[4];
  {
    const bf16* qp = q_lat + ((size_t)(boff + q0 + li)) * 1024 + h * 64 + hb * 8;
#pragma unroll
    for (int s = 0; s < 4; ++s) qf[s] = *(const bf16x8*)(qp + 16 * s);
  }

  float m_r = -3e38f, lsum = 0.f;
  f32x16 ot0 = {}, ot1 = {};

  auto tilecompute = [&](const bf16x8 (&ka)[4], const bf16x8 (&va)[2][2], int t) {
    f32x16 st = {};
    __builtin_amdgcn_s_setprio(1);
#pragma unroll
    for (int s = 0; s < 4; ++s) st = MFMA32x32x16(ka[s], qf[s], st);
    __builtin_amdgcn_s_setprio(0);
    float p[16];
#pragma unroll
    for (int r = 0; r < 16; ++r) p[r] = st[r];
    if (t == nt - 1) {  // diagonal tile mask: k_local > q_local
#pragma unroll
      for (int r = 0; r < 16; ++r) {
        const int krow = (r & 3) + 8 * (r >> 2) + 4 * hb;
        if (krow > li) p[r] = -30000.f;
      }
    }
    float pmax = fmaxf(fmaxf(fmaxf(p[0], p[1]), fmaxf(p[2], p[3])),
                       fmaxf(fmaxf(p[4], p[5]), fmaxf(p[6], p[7])));
    pmax = fmaxf(pmax, fmaxf(fmaxf(fmaxf(p[8], p[9]), fmaxf(p[10], p[11])),
                             fmaxf(fmaxf(p[12], p[13]), fmaxf(p[14], p[15]))));
    pmax = fmaxf(pmax, __shfl_xor(pmax, 32));
    // defer-max: only rescale when the running max is badly stale (T13)
    if (!__all(pmax <= m_r + 8.0f)) {
      const float mnew = fmaxf(m_r, pmax);
      const float alpha = exp2f(m_r - mnew);
      m_r = mnew;
      lsum *= alpha;
#pragma unroll
      for (int r = 0; r < 16; ++r) { ot0[r] *= alpha; ot1[r] *= alpha; }
    }
    float rs = 0.f;
#pragma unroll
    for (int r = 0; r < 16; ++r) {
      p[r] = exp2f(p[r] - m_r);  // bounded by 2^8
      rs += p[r];
    }
    rs += __shfl_xor(rs, 32);
    lsum += rs;
    // P^T B-fragments via shfl_xor(32) exchange (R4-verified layout)
    const unsigned A0 = packbf(p[0], p[1]), A1 = packbf(p[2], p[3]);
    const unsigned B0 = packbf(p[4], p[5]), B1 = packbf(p[6], p[7]);
    const unsigned C0 = packbf(p[8], p[9]), C1 = packbf(p[10], p[11]);
    const unsigned D0 = packbf(p[12], p[13]), D1 = packbf(p[14], p[15]);
    const unsigned sA0 = (unsigned)__shfl_xor((int)A0, 32), sA1 = (unsigned)__shfl_xor((int)A1, 32);
    const unsigned sB0 = (unsigned)__shfl_xor((int)B0, 32), sB1 = (unsigned)__shfl_xor((int)B1, 32);
    const unsigned sC0 = (unsigned)__shfl_xor((int)C0, 32), sC1 = (unsigned)__shfl_xor((int)C1, 32);
    const unsigned sD0 = (unsigned)__shfl_xor((int)D0, 32), sD1 = (unsigned)__shfl_xor((int)D1, 32);
    u32x4 w1 = hb ? (u32x4){sB0, sB1, B0, B1} : (u32x4){A0, A1, sA0, sA1};
    u32x4 w2 = hb ? (u32x4){sD0, sD1, D0, D1} : (u32x4){C0, C1, sC0, sC1};
    const bf16x8 pb1 = __builtin_bit_cast(bf16x8, w1);
    const bf16x8 pb2 = __builtin_bit_cast(bf16x8, w2);
    __builtin_amdgcn_s_setprio(1);
    ot0 = MFMA32x32x16(va[0][0], pb1, ot0);
    ot0 = MFMA32x32x16(va[0][1], pb2, ot0);
    ot1 = MFMA32x32x16(va[1][0], pb1, ot1);
    ot1 = MFMA32x32x16(va[1][1], pb2, ot1);
    __builtin_amdgcn_s_setprio(0);
  };

  bf16x8 kaA[4], vaA[2][2], kaB[4], vaB[2][2];
  loadK(kaA, 0);
  loadV(vaA, 0);
  int t = 0;
  while (true) {
    if (t + 1 < nt) { loadK(kaB, (t + 1) * 32); loadV(vaB, (t + 1) * 32); }
    tilecompute(kaA, vaA, t);
    ++t;
    if (t == nt) break;
    if (t + 1 < nt) { loadK(kaA, (t + 1) * 32); loadV(vaA, (t + 1) * 32); }
    tilecompute(kaB, vaB, t);
    ++t;
    if (t == nt) break;
  }

  // epilogue: O^T regs -> per-wave LDS transpose -> coalesced store
  const float inv = 1.0f / lsum;
#pragma unroll
  for (int r = 0; r < 16; ++r) {
    const int ldr = (r & 3) + 8 * (r >> 2) + 4 * hb;
    etile[w][li][ldr] = (bf16)(ot0[r] * inv);
    etile[w][li][ldr + 32] = (bf16)(ot1[r] * inv);
  }
  asm volatile("s_waitcnt lgkmcnt(0)" ::: "memory");
  __builtin_amdgcn_sched_barrier(0);
  {
    bf16* op = out_lat + ((size_t)(boff + q0 + li)) * 1024 + h * 64 + hb * 32;
#pragma unroll
    for (int j = 0; j < 4; ++j)
      *(bf16x8*)(op + 8 * j) = *(const bf16x8*)&etile[w][li][hb * 32 + 8 * j];
  }
}

// ---------------- host launch ----------------
extern "C" void kernel_launch(void* const* d_in, const int* in_sizes, int n_in,
                              void* d_out, int out_size, void* d_ws, size_t ws_size,
                              hipStream_t stream) {
  const float* x   = (const float*)d_in[0];
  const float* w_c = (const float*)d_in[1];
  const float* w_k = (const float*)d_in[2];
  const float* w_v = (const float*)d_in[3];
  const float* w_q = (const float*)d_in[4];
  const float* w_o = (const float*)d_in[5];
  float* out = (float*)d_out;

  char* ws = (char*)d_ws;
  size_t off = 0;
  auto alloc = [&](size_t bytes) {
    char* p = ws + off;
    off += (bytes + 255) & ~(size_t)255;
    return p;
  };
  bf16*  xb      = (bf16*)alloc((size_t)4096 * 1024 * 2);
  float* latpart = (float*)alloc((size_t)8 * 4096 * 64 * 4);
  bf16*  latent  = (bf16*)alloc((size_t)4096 * 64 * 2);
  bf16*  latT    = (bf16*)alloc((size_t)64 * 4096 * 2);
  bf16*  qlat    = (bf16*)alloc((size_t)4096 * 1024 * 2);
  bf16*  outlat  = (bf16*)alloc((size_t)4096 * 1024 * 2);
  bf16*  wcT     = (bf16*)alloc((size_t)64 * 1024 * 2);
  bf16*  WqlatT  = (bf16*)alloc((size_t)1024 * 1024 * 2);
  bf16*  WoutT   = (bf16*)alloc((size_t)1024 * 1024 * 2);

  cvt_f32_bf16<<<4096, 256, 0, stream>>>(x, xb, 1048576);
  transpose_cvt_tiled<<<dim3(1, 16), 256, 0, stream>>>(w_c, wcT, 1024, 64);
  prep_wqlat<<<dim3(16, 16), 256, 0, stream>>>(w_q, w_k, WqlatT);
  prep_wout<<<dim3(16, 16), 256, 0, stream>>>(w_v, w_o, WoutT);

  // latent partials: K split 8 ways -> [8][4096][64] f32
  gemm_bf16<128, 64, 2, 2, true><<<dim3(32, 1, 8), 256, 0, stream>>>(
      xb, wcT, latpart, 64, 128, (size_t)4096 * 64);
  cvt_lat<<<64, 256, 0, stream>>>(latpart, latent, latT);

  // q_lat = xb @ W_qlatT (scale folded); 512 blocks = 2/CU
  gemm_bf16<64, 128, 1, 4, false><<<dim3(64, 8), 256, 0, stream>>>(
      xb, WqlatT, qlat, 1024, 1024, 0);

  // attention: 2048 wave-jobs, 4 waves/block, 512 blocks
  mla_attn2<<<512, 256, 0, stream>>>(qlat, latent, latT, outlat);

  // out = out_lat @ W_outT (fp32); 512 blocks = 2/CU
  gemm_bf16<64, 128, 1, 4, true><<<dim3(64, 8), 256, 0, stream>>>(
      outlat, WoutT, (void*)out, 1024, 1024, 0);

  (void)in_sizes; (void)n_in; (void)out_size; (void)ws_size;
}